// Round 2
// baseline (9424.958 us; speedup 1.0000x reference)
//
#include <hip/hip_runtime.h>
#include <math.h>

#define N_    2048
#define D0_   256
#define D1_   128
#define D2_   32
#define F_    416
#define H_    4
#define DH_   64
#define L_    4
#define NC_   10
#define C2_   1.7320508075688772f

// ---------------- generic tiled f32 GEMM with epilogue ----------------
// MODE 0: C = A@B (+bias)      MODE 1: C = silu(A@B)
// MODE 2: C = sigmoid(A@B)     MODE 3: C = Cres + A@B
template<int MODE>
__global__ void gemm_f32(const float* __restrict__ A, const float* __restrict__ B,
                         const float* __restrict__ bias, const float* __restrict__ Cres,
                         float* __restrict__ C, int M, int K, int Nn) {
    __shared__ float As[16][65];
    __shared__ float Bs[16][65];
    const int bm = blockIdx.y * 64, bn = blockIdx.x * 64;
    const int t = threadIdx.x;
    const int tm = (t / 16) * 4, tn = (t % 16) * 4;
    float acc[4][4] = {};
    for (int k0 = 0; k0 < K; k0 += 16) {
        for (int i = t; i < 64 * 16; i += 256) {
            int mm = i >> 4, kk = i & 15;
            int row = bm + mm, kidx = k0 + kk;
            As[kk][mm] = (row < M && kidx < K) ? A[(size_t)row * K + kidx] : 0.f;
        }
        for (int i = t; i < 16 * 64; i += 256) {
            int kk = i >> 6, nn = i & 63;
            int kidx = k0 + kk, col = bn + nn;
            Bs[kk][nn] = (kidx < K && col < Nn) ? B[(size_t)kidx * Nn + col] : 0.f;
        }
        __syncthreads();
#pragma unroll
        for (int kk = 0; kk < 16; ++kk) {
            float a4[4], b4[4];
#pragma unroll
            for (int i = 0; i < 4; ++i) a4[i] = As[kk][tm + i];
#pragma unroll
            for (int j = 0; j < 4; ++j) b4[j] = Bs[kk][tn + j];
#pragma unroll
            for (int i = 0; i < 4; ++i)
#pragma unroll
                for (int j = 0; j < 4; ++j)
                    acc[i][j] = fmaf(a4[i], b4[j], acc[i][j]);
        }
        __syncthreads();
    }
    for (int i = 0; i < 4; ++i) {
        int row = bm + tm + i;
        if (row >= M) continue;
        for (int j = 0; j < 4; ++j) {
            int col = bn + tn + j;
            if (col >= Nn) continue;
            float v = acc[i][j];
            if (bias) v += bias[col];
            if (MODE == 1) v = v / (1.f + expf(-v));
            if (MODE == 2) v = 1.f / (1.f + expf(-v));
            if (MODE == 3) v += Cres[(size_t)row * Nn + col];
            C[(size_t)row * Nn + col] = v;
        }
    }
}

// ---------------- invariants: [x0 | ||x1|| | ||x2||] -> inv [N,416] ----------------
__global__ void invar_kernel(const float* __restrict__ x0, const float* __restrict__ x1,
                             const float* __restrict__ x2, float* __restrict__ inv) {
    int n = blockIdx.x, t = threadIdx.x;
    inv[(size_t)n * F_ + t] = x0[(size_t)n * D0_ + t];
    if (t < 128) {
        const float* p = x1 + (size_t)n * 384 + t * 3;
        inv[(size_t)n * F_ + 256 + t] = sqrtf(p[0]*p[0] + p[1]*p[1] + p[2]*p[2]);
    }
    if (t < 32) {
        const float* p = x2 + (size_t)n * 160 + t * 5;
        inv[(size_t)n * F_ + 384 + t] =
            sqrtf(p[0]*p[0] + p[1]*p[1] + p[2]*p[2] + p[3]*p[3] + p[4]*p[4]);
    }
}

// ---------------- v1[m,e,c] = sum_d x1[m,d,c] * Wv1[d,e] ----------------
__global__ void v1_kernel(const float* __restrict__ x1, const float* __restrict__ W,
                          float* __restrict__ v1) {
    int m = blockIdx.x, t = threadIdx.x;  // 384 threads
    __shared__ float sh[384];
    sh[t] = x1[(size_t)m * 384 + t];
    __syncthreads();
    int e = t / 3, c = t % 3;
    float acc = 0.f;
#pragma unroll 4
    for (int d = 0; d < 128; ++d)
        acc = fmaf(sh[d * 3 + c], W[d * 128 + e], acc);
    v1[(size_t)m * 384 + t] = acc;
}

__global__ void v2_kernel(const float* __restrict__ x2, const float* __restrict__ W,
                          float* __restrict__ v2) {
    int m = blockIdx.x, t = threadIdx.x;  // 192 threads, 160 active
    __shared__ float sh[160];
    if (t < 160) sh[t] = x2[(size_t)m * 160 + t];
    __syncthreads();
    if (t < 160) {
        int e = t / 5, c = t % 5;
        float acc = 0.f;
#pragma unroll 4
        for (int d = 0; d < 32; ++d)
            acc = fmaf(sh[d * 5 + c], W[d * 32 + e], acc);
        v2[(size_t)m * 160 + t] = acc;
    }
}

// ---------------- scores + softmax for one head; attnh[n,m] ----------------
__global__ void attn_kernel(const float* __restrict__ q, const float* __restrict__ k,
                            float* __restrict__ attnh, int h) {
    int n = blockIdx.x, t = threadIdx.x;  // 256 threads
    __shared__ float qs[64];
    __shared__ float red[256];
    if (t < 64) qs[t] = q[(size_t)n * D0_ + h * DH_ + t];
    __syncthreads();
    float s[8];
#pragma unroll
    for (int i = 0; i < 8; ++i) {
        int m = i * 256 + t;
        const float4* kp = (const float4*)(k + (size_t)m * D0_ + h * DH_);
        float acc = 0.f;
#pragma unroll
        for (int d4 = 0; d4 < 16; ++d4) {
            float4 kv = kp[d4];
            acc = fmaf(qs[4*d4+0], kv.x, acc);
            acc = fmaf(qs[4*d4+1], kv.y, acc);
            acc = fmaf(qs[4*d4+2], kv.z, acc);
            acc = fmaf(qs[4*d4+3], kv.w, acc);
        }
        s[i] = acc * 0.125f;  // 1/sqrt(64)
    }
    float mx = s[0];
#pragma unroll
    for (int i = 1; i < 8; ++i) mx = fmaxf(mx, s[i]);
    red[t] = mx; __syncthreads();
    for (int st = 128; st > 0; st >>= 1) { if (t < st) red[t] = fmaxf(red[t], red[t+st]); __syncthreads(); }
    mx = red[0]; __syncthreads();
    float sum = 0.f;
#pragma unroll
    for (int i = 0; i < 8; ++i) { s[i] = expf(s[i] - mx); sum += s[i]; }
    red[t] = sum; __syncthreads();
    for (int st = 128; st > 0; st >>= 1) { if (t < st) red[t] += red[t+st]; __syncthreads(); }
    float rinv = 1.f / red[0];
#pragma unroll
    for (int i = 0; i < 8; ++i)
        attnh[(size_t)n * N_ + i * 256 + t] = s[i] * rinv;
}

// ---------------- amean accumulate ----------------
template<bool INIT>
__global__ void amean_acc(const float* __restrict__ ah, float* __restrict__ am) {
    size_t i = (size_t)blockIdx.x * 256 + threadIdx.x;
    float v = 0.25f * ah[i];
    am[i] = INIT ? v : am[i] + v;
}

// ---------------- x0[n, h*64+c] += sum_m attnh[n,m] v0[m, h*64+c] ----------------
__global__ void agg0_kernel(const float* __restrict__ attnh, const float* __restrict__ v0,
                            float* __restrict__ x0, int h) {
    int n0 = blockIdx.x * 4;
    int t = threadIdx.x;           // 256 threads = 4 waves
    int w = t >> 6, c = t & 63;
    __shared__ float vs[64][65];
    __shared__ float as[4][64];
    float acc = 0.f;
    for (int m0 = 0; m0 < N_; m0 += 64) {
        __syncthreads();
        for (int i = t; i < 64 * 64; i += 256) {
            int mm = i >> 6, cc = i & 63;
            vs[mm][cc] = v0[(size_t)(m0 + mm) * D0_ + h * DH_ + cc];
        }
        { int nn = t >> 6, mm = t & 63;
          as[nn][mm] = attnh[(size_t)(n0 + nn) * N_ + m0 + mm]; }
        __syncthreads();
#pragma unroll 8
        for (int mm = 0; mm < 64; ++mm)
            acc = fmaf(as[w][mm], vs[mm][c], acc);
    }
    x0[(size_t)(n0 + w) * D0_ + h * DH_ + c] += acc;
}

// ---------------- degree-1: x1 += a@v1 + (a*Y1)@s1, Y recomputed on the fly ----------------
__global__ void deg1_kernel(const float* __restrict__ am, const float* __restrict__ pos,
                            const float* __restrict__ v1, const float* __restrict__ s1,
                            float* __restrict__ x1) {
    int n0 = blockIdx.x * 4;
    int t = threadIdx.x;           // 384 threads
    int d = t / 3, c = t % 3;
    __shared__ float as[4][32];
    __shared__ float ys[4][32][3];
    __shared__ float posn[4][3];
    if (t < 12) posn[t / 3][t % 3] = pos[(n0 + t / 3) * 3 + (t % 3)];
    float acc[4] = {0.f, 0.f, 0.f, 0.f};
    for (int m0 = 0; m0 < N_; m0 += 32) {
        __syncthreads();
        if (t < 128) {
            int nl = t >> 5, mm = t & 31;
            int m = m0 + mm;
            as[nl][mm] = am[(size_t)(n0 + nl) * N_ + m];
            float rx = pos[m*3+0] - posn[nl][0];
            float ry = pos[m*3+1] - posn[nl][1];
            float rz = pos[m*3+2] - posn[nl][2];
            float dist = sqrtf(rx*rx + ry*ry + rz*rz);
            float rinv = dist > 1e-6f ? 1.f / dist : 0.f;
            ys[nl][mm][0] = rx * rinv;
            ys[nl][mm][1] = ry * rinv;
            ys[nl][mm][2] = rz * rinv;
        }
        __syncthreads();
        for (int mm = 0; mm < 32; ++mm) {
            int m = m0 + mm;
            float v = v1[(size_t)m * 384 + t];
            float s = s1[(size_t)m * 128 + d];
#pragma unroll
            for (int nl = 0; nl < 4; ++nl) {
                float tmp = fmaf(ys[nl][mm][c], s, v);
                acc[nl] = fmaf(as[nl][mm], tmp, acc[nl]);
            }
        }
    }
#pragma unroll
    for (int nl = 0; nl < 4; ++nl)
        x1[(size_t)(n0 + nl) * 384 + t] += acc[nl];
}

// ---------------- degree-2: x2 += a@v2 + (a*Y2)@s2 ----------------
__global__ void deg2_kernel(const float* __restrict__ am, const float* __restrict__ pos,
                            const float* __restrict__ v2, const float* __restrict__ s2,
                            float* __restrict__ x2) {
    int n0 = blockIdx.x * 4;
    int t = threadIdx.x;           // 192 threads, 160 active
    int d = t / 5, c = t % 5;
    __shared__ float as[4][32];
    __shared__ float ys[4][32][5];
    __shared__ float posn[4][3];
    if (t < 12) posn[t / 3][t % 3] = pos[(n0 + t / 3) * 3 + (t % 3)];
    float acc[4] = {0.f, 0.f, 0.f, 0.f};
    for (int m0 = 0; m0 < N_; m0 += 32) {
        __syncthreads();
        if (t < 128) {
            int nl = t >> 5, mm = t & 31;
            int m = m0 + mm;
            as[nl][mm] = am[(size_t)(n0 + nl) * N_ + m];
            float rx = pos[m*3+0] - posn[nl][0];
            float ry = pos[m*3+1] - posn[nl][1];
            float rz = pos[m*3+2] - posn[nl][2];
            float dist = sqrtf(rx*rx + ry*ry + rz*rz);
            float valid = dist > 1e-6f ? 1.f : 0.f;
            float rinv = dist > 1e-6f ? 1.f / dist : 0.f;
            float ux = rx * rinv, uy = ry * rinv, uz = rz * rinv;
            ys[nl][mm][0] = C2_ * ux * uy;
            ys[nl][mm][1] = C2_ * uy * uz;
            ys[nl][mm][2] = valid * 0.5f * (3.f * uz * uz - 1.f);
            ys[nl][mm][3] = C2_ * ux * uz;
            ys[nl][mm][4] = 0.5f * C2_ * (ux * ux - uy * uy);
        }
        __syncthreads();
        if (t < 160) {
            for (int mm = 0; mm < 32; ++mm) {
                int m = m0 + mm;
                float v = v2[(size_t)m * 160 + t];
                float s = s2[(size_t)m * 32 + d];
#pragma unroll
                for (int nl = 0; nl < 4; ++nl) {
                    float tmp = fmaf(ys[nl][mm][c], s, v);
                    acc[nl] = fmaf(as[nl][mm], tmp, acc[nl]);
                }
            }
        }
    }
    if (t < 160) {
#pragma unroll
        for (int nl = 0; nl < 4; ++nl)
            x2[(size_t)(n0 + nl) * 160 + t] += acc[nl];
    }
}

// ---------------- gating: x1 *= g[:, :128], x2 *= g[:, 128:] ----------------
__global__ void gate_kernel(const float* __restrict__ g, float* __restrict__ x1,
                            float* __restrict__ x2) {
    int idx = blockIdx.x * 256 + threadIdx.x;
    const int n1 = N_ * 384;
    const int total = n1 + N_ * 160;
    if (idx >= total) return;
    if (idx < n1) {
        int n = idx / 384, d = (idx % 384) / 3;
        x1[idx] *= g[n * 160 + d];
    } else {
        int j = idx - n1;
        int n = j / 160, d = (j % 160) / 5;
        x2[j] *= g[n * 160 + 128 + d];
    }
}

extern "C" void kernel_launch(void* const* d_in, const int* in_sizes, int n_in,
                              void* d_out, int out_size, void* d_ws, size_t ws_size,
                              hipStream_t stream) {
    const float* x    = (const float*)d_in[0];
    const float* pos  = (const float*)d_in[1];
    const float* embW = (const float*)d_in[2];
    const float* embB = (const float*)d_in[3];
    const float* Wq   = (const float*)d_in[4];
    const float* Wk   = (const float*)d_in[5];
    const float* Wv0  = (const float*)d_in[6];
    const float* Wv1  = (const float*)d_in[7];
    const float* Wv2  = (const float*)d_in[8];
    const float* Ws1  = (const float*)d_in[9];
    const float* Ws2  = (const float*)d_in[10];
    const float* Wffa = (const float*)d_in[11];
    const float* Wffb = (const float*)d_in[12];
    const float* Wg   = (const float*)d_in[13];
    const float* outW = (const float*)d_in[14];
    const float* outB = (const float*)d_in[15];
    float* out = (float*)d_out;

    float* p = (float*)d_ws;
    float* x0  = p; p += N_ * D0_;
    float* x1  = p; p += N_ * D1_ * 3;
    float* x2  = p; p += N_ * D2_ * 5;
    float* inv = p; p += N_ * F_;
    float* q   = p; p += N_ * D0_;
    float* k   = p; p += N_ * D0_;
    float* ah  = p; p += (size_t)N_ * N_;   // per-head attention
    float* am  = p; p += (size_t)N_ * N_;   // head-mean attention
    float* v0  = p; p += N_ * D0_;
    float* v1  = p; p += N_ * D1_ * 3;
    float* v2  = p; p += N_ * D2_ * 5;
    float* s1  = p; p += N_ * D1_;
    float* s2  = p; p += N_ * D2_;
    float* fft = p; p += N_ * 512;
    float* gm  = p; p += N_ * 160;

    hipMemsetAsync(x1, 0, (size_t)N_ * D1_ * 3 * sizeof(float), stream);
    hipMemsetAsync(x2, 0, (size_t)N_ * D2_ * 5 * sizeof(float), stream);

    auto gemm = [&](int mode, const float* A, const float* B, const float* bias,
                    const float* Cres, float* C, int M, int K, int Nc) {
        dim3 g((Nc + 63) / 64, (M + 63) / 64);
        switch (mode) {
            case 0: gemm_f32<0><<<g, 256, 0, stream>>>(A, B, bias, Cres, C, M, K, Nc); break;
            case 1: gemm_f32<1><<<g, 256, 0, stream>>>(A, B, bias, Cres, C, M, K, Nc); break;
            case 2: gemm_f32<2><<<g, 256, 0, stream>>>(A, B, bias, Cres, C, M, K, Nc); break;
            case 3: gemm_f32<3><<<g, 256, 0, stream>>>(A, B, bias, Cres, C, M, K, Nc); break;
        }
    };

    // embedding
    gemm(0, x, embW, embB, nullptr, x0, N_, 118, D0_);

    for (int l = 0; l < L_; ++l) {
        const float* Wq_l   = Wq   + (size_t)l * F_ * 256;
        const float* Wk_l   = Wk   + (size_t)l * F_ * 256;
        const float* Wv0_l  = Wv0  + (size_t)l * 256 * 256;
        const float* Wv1_l  = Wv1  + (size_t)l * 128 * 128;
        const float* Wv2_l  = Wv2  + (size_t)l * 32 * 32;
        const float* Ws1_l  = Ws1  + (size_t)l * 256 * 128;
        const float* Ws2_l  = Ws2  + (size_t)l * 256 * 32;
        const float* Wffa_l = Wffa + (size_t)l * 256 * 512;
        const float* Wffb_l = Wffb + (size_t)l * 512 * 256;
        const float* Wg_l   = Wg   + (size_t)l * F_ * 160;

        invar_kernel<<<N_, 256, 0, stream>>>(x0, x1, x2, inv);
        gemm(0, inv, Wq_l, nullptr, nullptr, q, N_, F_, 256);
        gemm(0, inv, Wk_l, nullptr, nullptr, k, N_, F_, 256);
        gemm(0, x0, Wv0_l, nullptr, nullptr, v0, N_, 256, 256);
        v1_kernel<<<N_, 384, 0, stream>>>(x1, Wv1_l, v1);
        v2_kernel<<<N_, 192, 0, stream>>>(x2, Wv2_l, v2);
        gemm(0, x0, Ws1_l, nullptr, nullptr, s1, N_, 256, 128);
        gemm(0, x0, Ws2_l, nullptr, nullptr, s2, N_, 256, 32);

        for (int h = 0; h < H_; ++h) {
            attn_kernel<<<N_, 256, 0, stream>>>(q, k, ah, h);
            if (h == 0) amean_acc<true><<<(N_ * N_) / 256, 256, 0, stream>>>(ah, am);
            else        amean_acc<false><<<(N_ * N_) / 256, 256, 0, stream>>>(ah, am);
            agg0_kernel<<<N_ / 4, 256, 0, stream>>>(ah, v0, x0, h);
        }

        deg1_kernel<<<N_ / 4, 384, 0, stream>>>(am, pos, v1, s1, x1);
        deg2_kernel<<<N_ / 4, 192, 0, stream>>>(am, pos, v2, s2, x2);

        gemm(1, x0, Wffa_l, nullptr, nullptr, fft, N_, 256, 512);
        gemm(3, fft, Wffb_l, nullptr, x0, x0, N_, 512, 256);

        invar_kernel<<<N_, 256, 0, stream>>>(x0, x1, x2, inv);
        gemm(2, inv, Wg_l, nullptr, nullptr, gm, N_, F_, 160);
        gate_kernel<<<(N_ * 544 + 255) / 256, 256, 0, stream>>>(gm, x1, x2);
    }

    gemm(0, x0, outW, outB, nullptr, out, N_, 256, NC_);
}

// Round 4
// 4537.754 us; speedup vs baseline: 2.0770x; 2.0770x over previous
//
#include <hip/hip_runtime.h>
#include <math.h>

#define N_    2048
#define D0_   256
#define D1_   128
#define D2_   32
#define F_    416
#define H_    4
#define DH_   64
#define L_    4
#define NC_   10
#define C2_   1.7320508075688772f

typedef unsigned short u16;
typedef __attribute__((ext_vector_type(8))) short short8v;
typedef __attribute__((ext_vector_type(4))) float f32x4;

union U8 { u16 u[8]; short8v v; };

__device__ __forceinline__ u16 f2bf(float f) {
    union { float f; unsigned int u; } x; x.f = f;
    unsigned int r = x.u + 0x7FFFu + ((x.u >> 16) & 1u);
    return (u16)(r >> 16);
}

__device__ __forceinline__ f32x4 mfma16(short8v a, short8v b, f32x4 c) {
    return __builtin_amdgcn_mfma_f32_16x16x32_bf16(a, b, c, 0, 0, 0);
}

// ================= MFMA GEMM: C(epi)= A[M,K] @ B, bf16 inputs, f32 accum ===========
// BLAY 0 (NN): B is [K,Nn] row-major.  BLAY 1 (NT): B is [Nn,K] row-major.
// EPI 0: C = scale*acc (+bias)   1: silu(acc)   2: sigmoid(acc)   3: C += acc
enum { B_NN = 0, B_NT = 1 };
enum { EPI_STORE = 0, EPI_SILU = 1, EPI_SIGMOID = 2, EPI_ACCUM = 3 };

template<int BLAY, int EPI>
__global__ __launch_bounds__(256) void mfma_gemm(
    const float* __restrict__ A, int lda,
    const float* __restrict__ B, int ldb,
    const float* __restrict__ bias,
    float* __restrict__ C, int ldc,
    int M, int K, int Nn, float scale)
{
    __shared__ __align__(16) u16 As[64][40];
    __shared__ __align__(16) u16 Bs[64][40];
    const int t = threadIdx.x;
    const int bm = blockIdx.y * 64, bn = blockIdx.x * 64;
    const int lane = t & 63, w = t >> 6;
    const int r0 = (w >> 1) * 32, c0 = (w & 1) * 32;
    const int fr = lane & 15, fk = (lane >> 4) * 8;
    const int ml = t >> 2, k8 = (t & 3) * 8;
    f32x4 acc[2][2] = {};

    for (int k0 = 0; k0 < K; k0 += 32) {
        // ---- A stage: As[m][k] ----
        {
            U8 u;
            if (((lda & 3) == 0) && (k0 + 32 <= K)) {
                const float* ap = A + (size_t)(bm + ml) * lda + k0 + k8;
                float4 a0 = *(const float4*)ap;
                float4 a1 = *(const float4*)(ap + 4);
                u.u[0]=f2bf(a0.x); u.u[1]=f2bf(a0.y); u.u[2]=f2bf(a0.z); u.u[3]=f2bf(a0.w);
                u.u[4]=f2bf(a1.x); u.u[5]=f2bf(a1.y); u.u[6]=f2bf(a1.z); u.u[7]=f2bf(a1.w);
            } else {
#pragma unroll
                for (int j = 0; j < 8; ++j) {
                    int kk = k0 + k8 + j;
                    u.u[j] = f2bf(kk < K ? A[(size_t)(bm + ml) * lda + kk] : 0.f);
                }
            }
            *(short8v*)&As[ml][k8] = u.v;
        }
        // ---- B stage: Bs[n][k] ----
        {
            U8 u;
            if (BLAY == B_NT) {
                if (((ldb & 3) == 0) && (k0 + 32 <= K) && (bn + ml < Nn)) {
                    const float* bp = B + (size_t)(bn + ml) * ldb + k0 + k8;
                    float4 b0 = *(const float4*)bp;
                    float4 b1 = *(const float4*)(bp + 4);
                    u.u[0]=f2bf(b0.x); u.u[1]=f2bf(b0.y); u.u[2]=f2bf(b0.z); u.u[3]=f2bf(b0.w);
                    u.u[4]=f2bf(b1.x); u.u[5]=f2bf(b1.y); u.u[6]=f2bf(b1.z); u.u[7]=f2bf(b1.w);
                } else {
#pragma unroll
                    for (int j = 0; j < 8; ++j) {
                        int kk = k0 + k8 + j;
                        u.u[j] = f2bf((kk < K && bn + ml < Nn)
                                      ? B[(size_t)(bn + ml) * ldb + kk] : 0.f);
                    }
                }
            } else {
                int nc = bn + ml;
#pragma unroll
                for (int j = 0; j < 8; ++j) {
                    int kk = k0 + k8 + j;
                    u.u[j] = f2bf((kk < K && nc < Nn) ? B[(size_t)kk * ldb + nc] : 0.f);
                }
            }
            *(short8v*)&Bs[ml][k8] = u.v;
        }
        __syncthreads();
        short8v a0 = *(const short8v*)&As[r0 + fr][fk];
        short8v a1 = *(const short8v*)&As[r0 + 16 + fr][fk];
        short8v b0 = *(const short8v*)&Bs[c0 + fr][fk];
        short8v b1 = *(const short8v*)&Bs[c0 + 16 + fr][fk];
        acc[0][0] = mfma16(a0, b0, acc[0][0]);
        acc[0][1] = mfma16(a0, b1, acc[0][1]);
        acc[1][0] = mfma16(a1, b0, acc[1][0]);
        acc[1][1] = mfma16(a1, b1, acc[1][1]);
        __syncthreads();
    }
#pragma unroll
    for (int mi = 0; mi < 2; ++mi)
#pragma unroll
    for (int ni = 0; ni < 2; ++ni)
#pragma unroll
    for (int r = 0; r < 4; ++r) {
        int row = bm + r0 + mi * 16 + ((lane >> 4) << 2) + r;
        int col = bn + c0 + ni * 16 + fr;
        if (col >= Nn) continue;
        float v = acc[mi][ni][r];
        float* cp = C + (size_t)row * ldc + col;
        if (EPI == EPI_STORE)   *cp = v * scale + (bias ? bias[col] : 0.f);
        if (EPI == EPI_SILU)    *cp = v / (1.f + expf(-v));
        if (EPI == EPI_SIGMOID) *cp = 1.f / (1.f + expf(-v));
        if (EPI == EPI_ACCUM)   *cp += v;
    }
}

// ========== degree GEMM: x_deg[:, :, c] += am @ vC_c + (am*Yc) @ sB ==========
template<int DEG>
__global__ __launch_bounds__(256) void deg_gemm(
    const float* __restrict__ am, const float* __restrict__ pos,
    const float* __restrict__ vB, const float* __restrict__ sB,
    float* __restrict__ xo)
{
    constexpr int E  = (DEG == 1) ? 128 : 32;
    constexpr int CH = (DEG == 1) ? 3 : 5;
    const int c = blockIdx.z;
    __shared__ __align__(16) u16 As0[64][40], As1[64][40], Bs0[64][40], Bs1[64][40];
    const int t = threadIdx.x;
    const int bm = blockIdx.y * 64, bn = blockIdx.x * 64;
    const int lane = t & 63, w = t >> 6;
    const int r0 = (w >> 1) * 32, c0 = (w & 1) * 32;
    const int fr = lane & 15, fk = (lane >> 4) * 8;
    const int ml = t >> 2, k8 = (t & 3) * 8;
    const float pnx = pos[(bm + ml) * 3 + 0];
    const float pny = pos[(bm + ml) * 3 + 1];
    const float pnz = pos[(bm + ml) * 3 + 2];
    const float* vBc = vB + (size_t)c * N_ * E;
    f32x4 acc[2][2] = {};

    for (int m0 = 0; m0 < N_; m0 += 32) {
        const float* ap = am + (size_t)(bm + ml) * N_ + m0 + k8;
        float4 a0 = *(const float4*)ap;
        float4 a1 = *(const float4*)(ap + 4);
        float av[8] = {a0.x, a0.y, a0.z, a0.w, a1.x, a1.y, a1.z, a1.w};
        U8 u0, u1;
#pragma unroll
        for (int j = 0; j < 8; ++j) {
            int m = m0 + k8 + j;
            float px = pos[m * 3 + 0] - pnx;
            float py = pos[m * 3 + 1] - pny;
            float pz = pos[m * 3 + 2] - pnz;
            float dist = sqrtf(px * px + py * py + pz * pz);
            float rinv = dist > 1e-6f ? 1.f / dist : 0.f;
            float ux = px * rinv, uy = py * rinv, uz = pz * rinv;
            float y;
            if (DEG == 1) {
                y = (c == 0) ? ux : (c == 1) ? uy : uz;
            } else {
                if      (c == 0) y = C2_ * ux * uy;
                else if (c == 1) y = C2_ * uy * uz;
                else if (c == 2) y = dist > 1e-6f ? 0.5f * (3.f * uz * uz - 1.f) : 0.f;
                else if (c == 3) y = C2_ * ux * uz;
                else             y = 0.5f * C2_ * (ux * ux - uy * uy);
            }
            u0.u[j] = f2bf(av[j]);
            u1.u[j] = f2bf(av[j] * y);
        }
        *(short8v*)&As0[ml][k8] = u0.v;
        *(short8v*)&As1[ml][k8] = u1.v;
        {
            U8 b0u, b1u;
            int nc = bn + ml;
#pragma unroll
            for (int j = 0; j < 8; ++j) {
                int kk = m0 + k8 + j;
                b0u.u[j] = f2bf(nc < E ? vBc[(size_t)kk * E + nc] : 0.f);
                b1u.u[j] = f2bf(nc < E ? sB[(size_t)kk * E + nc] : 0.f);
            }
            *(short8v*)&Bs0[ml][k8] = b0u.v;
            *(short8v*)&Bs1[ml][k8] = b1u.v;
        }
        __syncthreads();
        short8v x0f = *(const short8v*)&As0[r0 + fr][fk];
        short8v x1f = *(const short8v*)&As0[r0 + 16 + fr][fk];
        short8v y0f = *(const short8v*)&As1[r0 + fr][fk];
        short8v y1f = *(const short8v*)&As1[r0 + 16 + fr][fk];
        short8v p0f = *(const short8v*)&Bs0[c0 + fr][fk];
        short8v p1f = *(const short8v*)&Bs0[c0 + 16 + fr][fk];
        short8v q0f = *(const short8v*)&Bs1[c0 + fr][fk];
        short8v q1f = *(const short8v*)&Bs1[c0 + 16 + fr][fk];
        acc[0][0] = mfma16(x0f, p0f, acc[0][0]);
        acc[0][1] = mfma16(x0f, p1f, acc[0][1]);
        acc[1][0] = mfma16(x1f, p0f, acc[1][0]);
        acc[1][1] = mfma16(x1f, p1f, acc[1][1]);
        acc[0][0] = mfma16(y0f, q0f, acc[0][0]);
        acc[0][1] = mfma16(y0f, q1f, acc[0][1]);
        acc[1][0] = mfma16(y1f, q0f, acc[1][0]);
        acc[1][1] = mfma16(y1f, q1f, acc[1][1]);
        __syncthreads();
    }
#pragma unroll
    for (int mi = 0; mi < 2; ++mi)
#pragma unroll
    for (int ni = 0; ni < 2; ++ni)
#pragma unroll
    for (int r = 0; r < 4; ++r) {
        int row = bm + r0 + mi * 16 + ((lane >> 4) << 2) + r;
        int col = bn + c0 + ni * 16 + fr;
        if (col >= E) continue;
        xo[(size_t)row * (E * CH) + col * CH + c] += acc[mi][ni][r];
    }
}

// ---------------- invariants ----------------
__global__ void invar_kernel(const float* __restrict__ x0, const float* __restrict__ x1,
                             const float* __restrict__ x2, float* __restrict__ inv) {
    int n = blockIdx.x, t = threadIdx.x;
    inv[(size_t)n * F_ + t] = x0[(size_t)n * D0_ + t];
    if (t < 128) {
        const float* p = x1 + (size_t)n * 384 + t * 3;
        inv[(size_t)n * F_ + 256 + t] = sqrtf(p[0]*p[0] + p[1]*p[1] + p[2]*p[2]);
    }
    if (t < 32) {
        const float* p = x2 + (size_t)n * 160 + t * 5;
        inv[(size_t)n * F_ + 384 + t] =
            sqrtf(p[0]*p[0] + p[1]*p[1] + p[2]*p[2] + p[3]*p[3] + p[4]*p[4]);
    }
}

// ---------------- v1c[c][m][e] = sum_d x1[m,d,c] Wv1[d,e] ----------------
__global__ void v1_kernel(const float* __restrict__ x1, const float* __restrict__ W,
                          float* __restrict__ v1c) {
    int m = blockIdx.x, t = threadIdx.x;  // 384
    __shared__ float sh[384];
    sh[t] = x1[(size_t)m * 384 + t];
    __syncthreads();
    int c = t >> 7, e = t & 127;
    float acc = 0.f;
#pragma unroll 4
    for (int d = 0; d < 128; ++d)
        acc = fmaf(sh[d * 3 + c], W[d * 128 + e], acc);
    v1c[(size_t)c * N_ * 128 + (size_t)m * 128 + e] = acc;
}

__global__ void v2_kernel(const float* __restrict__ x2, const float* __restrict__ W,
                          float* __restrict__ v2c) {
    int m = blockIdx.x, t = threadIdx.x;  // 192, 160 active
    __shared__ float sh[160];
    if (t < 160) sh[t] = x2[(size_t)m * 160 + t];
    __syncthreads();
    if (t < 160) {
        int c = t >> 5, e = t & 31;
        float acc = 0.f;
#pragma unroll 4
        for (int d = 0; d < 32; ++d)
            acc = fmaf(sh[d * 5 + c], W[d * 32 + e], acc);
        v2c[(size_t)c * N_ * 32 + (size_t)m * 32 + e] = acc;
    }
}

// ---------------- softmax rows of S in place + accumulate head-mean ----------------
template<bool INIT>
__global__ void softmax_am(float* __restrict__ S, float* __restrict__ am) {
    int n = blockIdx.x, t = threadIdx.x;  // 256 threads
    __shared__ float red[256];
    float* Sp = S + (size_t)n * N_;
    float s[8];
#pragma unroll
    for (int i = 0; i < 8; ++i) s[i] = Sp[i * 256 + t];
    float mx = s[0];
#pragma unroll
    for (int i = 1; i < 8; ++i) mx = fmaxf(mx, s[i]);
    red[t] = mx; __syncthreads();
    for (int st = 128; st > 0; st >>= 1) { if (t < st) red[t] = fmaxf(red[t], red[t + st]); __syncthreads(); }
    mx = red[0]; __syncthreads();
    float sum = 0.f;
#pragma unroll
    for (int i = 0; i < 8; ++i) { s[i] = expf(s[i] - mx); sum += s[i]; }
    red[t] = sum; __syncthreads();
    for (int st = 128; st > 0; st >>= 1) { if (t < st) red[t] += red[t + st]; __syncthreads(); }
    float rinv = 1.f / red[0];
#pragma unroll
    for (int i = 0; i < 8; ++i) {
        float pv = s[i] * rinv;
        Sp[i * 256 + t] = pv;
        float* amp = am + (size_t)n * N_ + i * 256 + t;
        *amp = INIT ? 0.25f * pv : *amp + 0.25f * pv;
    }
}

// ---------------- gating ----------------
__global__ void gate_kernel(const float* __restrict__ g, float* __restrict__ x1,
                            float* __restrict__ x2) {
    int idx = blockIdx.x * 256 + threadIdx.x;
    const int n1 = N_ * 384;
    const int total = n1 + N_ * 160;
    if (idx >= total) return;
    if (idx < n1) {
        int n = idx / 384, d = (idx % 384) / 3;
        x1[idx] *= g[n * 160 + d];
    } else {
        int j = idx - n1;
        int n = j / 160, d = (j % 160) / 5;
        x2[j] *= g[n * 160 + 128 + d];
    }
}

extern "C" void kernel_launch(void* const* d_in, const int* in_sizes, int n_in,
                              void* d_out, int out_size, void* d_ws, size_t ws_size,
                              hipStream_t stream) {
    const float* x    = (const float*)d_in[0];
    const float* pos  = (const float*)d_in[1];
    const float* embW = (const float*)d_in[2];
    const float* embB = (const float*)d_in[3];
    const float* Wq   = (const float*)d_in[4];
    const float* Wk   = (const float*)d_in[5];
    const float* Wv0  = (const float*)d_in[6];
    const float* Wv1  = (const float*)d_in[7];
    const float* Wv2  = (const float*)d_in[8];
    const float* Ws1  = (const float*)d_in[9];
    const float* Ws2  = (const float*)d_in[10];
    const float* Wffa = (const float*)d_in[11];
    const float* Wffb = (const float*)d_in[12];
    const float* Wg   = (const float*)d_in[13];
    const float* outW = (const float*)d_in[14];
    const float* outB = (const float*)d_in[15];
    float* out = (float*)d_out;

    float* p = (float*)d_ws;
    float* x0  = p; p += N_ * D0_;
    float* x1  = p; p += N_ * D1_ * 3;
    float* x2  = p; p += N_ * D2_ * 5;
    float* inv = p; p += N_ * F_;
    float* q   = p; p += N_ * D0_;
    float* k   = p; p += N_ * D0_;
    float* S   = p; p += (size_t)N_ * N_;
    float* am  = p; p += (size_t)N_ * N_;
    float* v0  = p; p += N_ * D0_;
    float* v1c = p; p += N_ * D1_ * 3;
    float* v2c = p; p += N_ * D2_ * 5;
    float* s1  = p; p += N_ * D1_;
    float* s2  = p; p += N_ * D2_;
    float* fft = p; p += N_ * 512;
    float* gm  = p; p += N_ * 160;

    hipMemsetAsync(x1, 0, (size_t)N_ * D1_ * 3 * sizeof(float), stream);
    hipMemsetAsync(x2, 0, (size_t)N_ * D2_ * 5 * sizeof(float), stream);

    auto grid = [](int M, int Nn) { return dim3((Nn + 63) / 64, M / 64); };

    // embedding: x0 = x @ embW + embB   (K=118 -> guarded path)
    mfma_gemm<B_NN, EPI_STORE><<<grid(N_, 256), 256, 0, stream>>>(
        x, 118, embW, 256, embB, x0, 256, N_, 118, 256, 1.f);

    for (int l = 0; l < L_; ++l) {
        const float* Wq_l   = Wq   + (size_t)l * F_ * 256;
        const float* Wk_l   = Wk   + (size_t)l * F_ * 256;
        const float* Wv0_l  = Wv0  + (size_t)l * 256 * 256;
        const float* Wv1_l  = Wv1  + (size_t)l * 128 * 128;
        const float* Wv2_l  = Wv2  + (size_t)l * 32 * 32;
        const float* Ws1_l  = Ws1  + (size_t)l * 256 * 128;
        const float* Ws2_l  = Ws2  + (size_t)l * 256 * 32;
        const float* Wffa_l = Wffa + (size_t)l * 256 * 512;
        const float* Wffb_l = Wffb + (size_t)l * 512 * 256;
        const float* Wg_l   = Wg   + (size_t)l * F_ * 160;

        invar_kernel<<<N_, 256, 0, stream>>>(x0, x1, x2, inv);
        mfma_gemm<B_NN, EPI_STORE><<<grid(N_, 256), 256, 0, stream>>>(
            inv, F_, Wq_l, 256, nullptr, q, 256, N_, F_, 256, 1.f);
        mfma_gemm<B_NN, EPI_STORE><<<grid(N_, 256), 256, 0, stream>>>(
            inv, F_, Wk_l, 256, nullptr, k, 256, N_, F_, 256, 1.f);
        mfma_gemm<B_NN, EPI_STORE><<<grid(N_, 256), 256, 0, stream>>>(
            x0, 256, Wv0_l, 256, nullptr, v0, 256, N_, 256, 256, 1.f);
        mfma_gemm<B_NN, EPI_STORE><<<grid(N_, 128), 256, 0, stream>>>(
            x0, 256, Ws1_l, 128, nullptr, s1, 128, N_, 256, 128, 1.f);
        mfma_gemm<B_NN, EPI_STORE><<<grid(N_, 32), 256, 0, stream>>>(
            x0, 256, Ws2_l, 32, nullptr, s2, 32, N_, 256, 32, 1.f);
        v1_kernel<<<N_, 384, 0, stream>>>(x1, Wv1_l, v1c);
        v2_kernel<<<N_, 192, 0, stream>>>(x2, Wv2_l, v2c);

        for (int h = 0; h < H_; ++h) {
            // S = (q_h @ k_h^T) / 8
            mfma_gemm<B_NT, EPI_STORE><<<grid(N_, N_), 256, 0, stream>>>(
                q + h * 64, 256, k + h * 64, 256, nullptr, S, N_, N_, 64, N_, 0.125f);
            if (h == 0) softmax_am<true ><<<N_, 256, 0, stream>>>(S, am);
            else        softmax_am<false><<<N_, 256, 0, stream>>>(S, am);
            // x0[:, h*64:+64] += S @ v0[:, h*64:+64]
            mfma_gemm<B_NN, EPI_ACCUM><<<grid(N_, 64), 256, 0, stream>>>(
                S, N_, v0 + h * 64, 256, nullptr, x0 + h * 64, 256, N_, N_, 64, 1.f);
        }

        deg_gemm<1><<<dim3(2, N_ / 64, 3), 256, 0, stream>>>(am, pos, v1c, s1, x1);
        deg_gemm<2><<<dim3(1, N_ / 64, 5), 256, 0, stream>>>(am, pos, v2c, s2, x2);

        mfma_gemm<B_NN, EPI_SILU><<<grid(N_, 512), 256, 0, stream>>>(
            x0, 256, Wffa_l, 512, nullptr, fft, 512, N_, 256, 512, 1.f);
        mfma_gemm<B_NN, EPI_ACCUM><<<grid(N_, 256), 256, 0, stream>>>(
            fft, 512, Wffb_l, 256, nullptr, x0, 256, N_, 512, 256, 1.f);

        invar_kernel<<<N_, 256, 0, stream>>>(x0, x1, x2, inv);
        mfma_gemm<B_NN, EPI_SIGMOID><<<grid(N_, 160), 256, 0, stream>>>(
            inv, F_, Wg_l, 160, nullptr, gm, 160, N_, F_, 160, 1.f);
        gate_kernel<<<(N_ * 544 + 255) / 256, 256, 0, stream>>>(gm, x1, x2);
    }

    mfma_gemm<B_NN, EPI_STORE><<<grid(N_, NC_), 256, 0, stream>>>(
        x0, 256, outW, NC_, outB, out, NC_, N_, 256, NC_, 1.f);
}

// Round 6
// 2025.673 us; speedup vs baseline: 4.6528x; 2.2401x over previous
//
#include <hip/hip_runtime.h>
#include <math.h>

#define N_    2048
#define D0_   256
#define D1_   128
#define D2_   32
#define F_    416
#define H_    4
#define DH_   64
#define L_    4
#define NC_   10
#define C2_   1.7320508075688772f
#define X12W  544   // x1 (128*3) | x2 (32*5) combined row width

typedef unsigned short u16;
typedef __attribute__((ext_vector_type(8))) short short8v;
typedef __attribute__((ext_vector_type(4))) float f32x4;

union U8 { u16 u[8]; short8v v; };

__device__ __forceinline__ u16 f2bf(float f) {
    union { float f; unsigned int u; } x; x.f = f;
    unsigned int r = x.u + 0x7FFFu + ((x.u >> 16) & 1u);
    return (u16)(r >> 16);
}
__device__ __forceinline__ float bf2f(u16 u) {
    union { float f; unsigned int u; } x; x.u = ((unsigned int)u) << 16;
    return x.f;
}

__device__ __forceinline__ f32x4 mfma16(short8v a, short8v b, f32x4 c) {
    return __builtin_amdgcn_mfma_f32_16x16x32_bf16(a, b, c, 0, 0, 0);
}

// ================= MFMA GEMM: C(epi)= A[M,K] @ B, bf16 inputs, f32 accum ===========
// BLAY 0 (NN): B is [K,Nn] row-major.  BLAY 1 (NT): B is [Nn,K] row-major.
// EPI 0: C = scale*acc (+bias)  1: silu  2: sigmoid  3: C += acc  4: atomicAdd (split-K)
enum { B_NN = 0, B_NT = 1 };
enum { EPI_STORE = 0, EPI_SILU = 1, EPI_SIGMOID = 2, EPI_ACCUM = 3, EPI_ATOMIC = 4 };

template<int BLAY, int EPI>
__global__ __launch_bounds__(256) void mfma_gemm(
    const float* __restrict__ A, int lda,
    const float* __restrict__ B, int ldb,
    const float* __restrict__ bias,
    float* __restrict__ C, int ldc,
    int M, int K, int Nn, float scale, int kchunk)
{
    __shared__ __align__(16) u16 As[64][40];
    __shared__ __align__(16) u16 Bs[64][40];
    const int t = threadIdx.x;
    const int bm = blockIdx.y * 64, bn = blockIdx.x * 64;
    const int lane = t & 63, w = t >> 6;
    const int r0 = (w >> 1) * 32, c0 = (w & 1) * 32;
    const int fr = lane & 15, fk = (lane >> 4) * 8;
    const int ml = t >> 2, k8 = (t & 3) * 8;
    const int kbeg = blockIdx.z * kchunk;
    const int kend = (kbeg + kchunk < K) ? kbeg + kchunk : K;
    f32x4 acc[2][2] = {};

    for (int k0 = kbeg; k0 < kend; k0 += 32) {
        // ---- A stage: As[m][k] ----
        {
            U8 u;
            if (((lda & 3) == 0) && (k0 + 32 <= kend)) {
                const float* ap = A + (size_t)(bm + ml) * lda + k0 + k8;
                float4 a0 = *(const float4*)ap;
                float4 a1 = *(const float4*)(ap + 4);
                u.u[0]=f2bf(a0.x); u.u[1]=f2bf(a0.y); u.u[2]=f2bf(a0.z); u.u[3]=f2bf(a0.w);
                u.u[4]=f2bf(a1.x); u.u[5]=f2bf(a1.y); u.u[6]=f2bf(a1.z); u.u[7]=f2bf(a1.w);
            } else {
#pragma unroll
                for (int j = 0; j < 8; ++j) {
                    int kk = k0 + k8 + j;
                    u.u[j] = f2bf(kk < kend ? A[(size_t)(bm + ml) * lda + kk] : 0.f);
                }
            }
            *(short8v*)&As[ml][k8] = u.v;
        }
        // ---- B stage: Bs[n][k] ----
        {
            U8 u;
            if (BLAY == B_NT) {
                if (((ldb & 3) == 0) && (k0 + 32 <= kend) && (bn + ml < Nn)) {
                    const float* bp = B + (size_t)(bn + ml) * ldb + k0 + k8;
                    float4 b0 = *(const float4*)bp;
                    float4 b1 = *(const float4*)(bp + 4);
                    u.u[0]=f2bf(b0.x); u.u[1]=f2bf(b0.y); u.u[2]=f2bf(b0.z); u.u[3]=f2bf(b0.w);
                    u.u[4]=f2bf(b1.x); u.u[5]=f2bf(b1.y); u.u[6]=f2bf(b1.z); u.u[7]=f2bf(b1.w);
                } else {
#pragma unroll
                    for (int j = 0; j < 8; ++j) {
                        int kk = k0 + k8 + j;
                        u.u[j] = f2bf((kk < kend && bn + ml < Nn)
                                      ? B[(size_t)(bn + ml) * ldb + kk] : 0.f);
                    }
                }
            } else {
                int nc = bn + ml;
#pragma unroll
                for (int j = 0; j < 8; ++j) {
                    int kk = k0 + k8 + j;
                    u.u[j] = f2bf((kk < kend && nc < Nn) ? B[(size_t)kk * ldb + nc] : 0.f);
                }
            }
            *(short8v*)&Bs[ml][k8] = u.v;
        }
        __syncthreads();
        short8v a0 = *(const short8v*)&As[r0 + fr][fk];
        short8v a1 = *(const short8v*)&As[r0 + 16 + fr][fk];
        short8v b0 = *(const short8v*)&Bs[c0 + fr][fk];
        short8v b1 = *(const short8v*)&Bs[c0 + 16 + fr][fk];
        acc[0][0] = mfma16(a0, b0, acc[0][0]);
        acc[0][1] = mfma16(a0, b1, acc[0][1]);
        acc[1][0] = mfma16(a1, b0, acc[1][0]);
        acc[1][1] = mfma16(a1, b1, acc[1][1]);
        __syncthreads();
    }
#pragma unroll
    for (int mi = 0; mi < 2; ++mi)
#pragma unroll
    for (int ni = 0; ni < 2; ++ni)
#pragma unroll
    for (int r = 0; r < 4; ++r) {
        int row = bm + r0 + mi * 16 + ((lane >> 4) << 2) + r;
        int col = bn + c0 + ni * 16 + fr;
        if (col >= Nn) continue;
        float v = acc[mi][ni][r];
        float* cp = C + (size_t)row * ldc + col;
        if (EPI == EPI_STORE)   *cp = v * scale + (bias ? bias[col] : 0.f);
        if (EPI == EPI_SILU)    *cp = v / (1.f + expf(-v));
        if (EPI == EPI_SIGMOID) *cp = 1.f / (1.f + expf(-v));
        if (EPI == EPI_ACCUM)   *cp += v;
        if (EPI == EPI_ATOMIC)  atomicAdd(cp, v);
    }
}

// ---------------- u precompute: U[c][n][m] bf16, c: 0=ux 1=uy 2=uz (24 MB) --------
__global__ void ucompute_kernel(const float* __restrict__ pos, u16* __restrict__ U) {
    int idx = blockIdx.x * 256 + threadIdx.x;     // N*N threads
    int n = idx >> 11, m = idx & (N_ - 1);
    float rx = pos[m * 3 + 0] - pos[n * 3 + 0];
    float ry = pos[m * 3 + 1] - pos[n * 3 + 1];
    float rz = pos[m * 3 + 2] - pos[n * 3 + 2];
    float d2 = rx * rx + ry * ry + rz * rz;
    bool valid = d2 > 1e-12f;
    float rinv = valid ? rsqrtf(d2) : 0.f;
    size_t base = (size_t)n * N_ + m;
    const size_t CS = (size_t)N_ * N_;
    U[base]          = f2bf(rx * rinv);
    U[base + CS]     = f2bf(ry * rinv);
    U[base + 2 * CS] = f2bf(rz * rinv);
}

// ============ fused mix GEMM: x12 += (am ⊙ Y_c) @ {s1|s2}, atomic, split-K ============
// grid.x = 11 tiles * 4 ksplit; tiles 0-5: deg1 (c=tile>>1, colbase=(tile&1)*64, B=s1)
//                               tiles 6-10: deg2 (c=tile-6, B=s2)
// Y_c synthesized from stored u: Y1 = u; Y2 from products of u with valid = ||u||^2>0.5.
__global__ __launch_bounds__(256) void mix_kernel(
    const float* __restrict__ am, const u16* __restrict__ U,
    const float* __restrict__ s1, const float* __restrict__ s2,
    float* __restrict__ x12)
{
    const int gx = blockIdx.x;
    const int ks = gx & 3, tile = gx >> 2;
    const int bm = blockIdx.y * 64;
    int cidx, colbase, Bld, Bcols, deg1;
    const float* Bp;
    if (tile < 6) { cidx = tile >> 1; colbase = (tile & 1) * 64; Bp = s1; Bld = 128; Bcols = 128; deg1 = 1; }
    else          { cidx = tile - 6; colbase = 0; Bp = s2; Bld = 32; Bcols = 32; deg1 = 0; }
    const size_t CS = (size_t)N_ * N_;
    __shared__ __align__(16) u16 As[64][40];
    __shared__ __align__(16) u16 Bs[64][40];
    const int t = threadIdx.x, lane = t & 63, w = t >> 6;
    const int r0 = (w >> 1) * 32, c0 = (w & 1) * 32;
    const int fr = lane & 15, fk = (lane >> 4) * 8;
    const int ml = t >> 2, k8 = (t & 3) * 8;
    const int kbeg = ks * (N_ / 4), kend = kbeg + N_ / 4;
    f32x4 acc[2][2] = {};

    for (int m0 = kbeg; m0 < kend; m0 += 32) {
        {   // A = am ⊙ Y_c (synthesized from u)
            const size_t off = (size_t)(bm + ml) * N_ + m0 + k8;
            const float* ap = am + off;
            float4 a0 = *(const float4*)ap;
            float4 a1 = *(const float4*)(ap + 4);
            float av[8] = {a0.x, a0.y, a0.z, a0.w, a1.x, a1.y, a1.z, a1.w};
            U8 u;
            if (deg1) {
                U8 yv; yv.v = *(const short8v*)(U + (size_t)cidx * CS + off);
#pragma unroll
                for (int j = 0; j < 8; ++j) u.u[j] = f2bf(av[j] * bf2f(yv.u[j]));
            } else {
                U8 xv, yv, zv;
                xv.v = *(const short8v*)(U + off);
                yv.v = *(const short8v*)(U + CS + off);
                zv.v = *(const short8v*)(U + 2 * CS + off);
#pragma unroll
                for (int j = 0; j < 8; ++j) {
                    float ux = bf2f(xv.u[j]), uy = bf2f(yv.u[j]), uz = bf2f(zv.u[j]);
                    float y;
                    if      (cidx == 0) y = C2_ * ux * uy;
                    else if (cidx == 1) y = C2_ * uy * uz;
                    else if (cidx == 2) y = (ux*ux + uy*uy + uz*uz > 0.5f)
                                            ? 0.5f * (3.f * uz * uz - 1.f) : 0.f;
                    else if (cidx == 3) y = C2_ * ux * uz;
                    else                y = 0.5f * C2_ * (ux * ux - uy * uy);
                    u.u[j] = f2bf(av[j] * y);
                }
            }
            *(short8v*)&As[ml][k8] = u.v;
        }
        {   // B = s1 or s2 (NN layout)
            int nc = colbase + ml;
            U8 u;
#pragma unroll
            for (int j = 0; j < 8; ++j) {
                int kk = m0 + k8 + j;
                u.u[j] = f2bf(nc < Bcols ? Bp[(size_t)kk * Bld + nc] : 0.f);
            }
            *(short8v*)&Bs[ml][k8] = u.v;
        }
        __syncthreads();
        short8v a0 = *(const short8v*)&As[r0 + fr][fk];
        short8v a1 = *(const short8v*)&As[r0 + 16 + fr][fk];
        short8v b0 = *(const short8v*)&Bs[c0 + fr][fk];
        short8v b1 = *(const short8v*)&Bs[c0 + 16 + fr][fk];
        acc[0][0] = mfma16(a0, b0, acc[0][0]);
        acc[0][1] = mfma16(a0, b1, acc[0][1]);
        acc[1][0] = mfma16(a1, b0, acc[1][0]);
        acc[1][1] = mfma16(a1, b1, acc[1][1]);
        __syncthreads();
    }
#pragma unroll
    for (int mi = 0; mi < 2; ++mi)
#pragma unroll
    for (int ni = 0; ni < 2; ++ni)
#pragma unroll
    for (int r = 0; r < 4; ++r) {
        int row = bm + r0 + mi * 16 + ((lane >> 4) << 2) + r;
        int col = colbase + c0 + ni * 16 + fr;
        float v = acc[mi][ni][r];
        if (deg1) {
            atomicAdd(&x12[(size_t)row * X12W + col * 3 + cidx], v);
        } else if (col < 32) {
            atomicAdd(&x12[(size_t)row * X12W + 384 + col * 5 + cidx], v);
        }
    }
}

// ---------------- invariants: [x0 | ||x1|| | ||x2||] -> inv [N,416] ----------------
__global__ void invar_kernel(const float* __restrict__ x0, const float* __restrict__ x12,
                             float* __restrict__ inv) {
    int n = blockIdx.x, t = threadIdx.x;
    inv[(size_t)n * F_ + t] = x0[(size_t)n * D0_ + t];
    if (t < 128) {
        const float* p = x12 + (size_t)n * X12W + t * 3;
        inv[(size_t)n * F_ + 256 + t] = sqrtf(p[0]*p[0] + p[1]*p[1] + p[2]*p[2]);
    }
    if (t < 32) {
        const float* p = x12 + (size_t)n * X12W + 384 + t * 5;
        inv[(size_t)n * F_ + 384 + t] =
            sqrtf(p[0]*p[0] + p[1]*p[1] + p[2]*p[2] + p[3]*p[3] + p[4]*p[4]);
    }
}

// ---------------- Vflat[m, e*3+c] = sum_d x1[m,d,c] Wv1[d,e]  (cols 0..383) --------
__global__ void v1_kernel(const float* __restrict__ x12, const float* __restrict__ W,
                          float* __restrict__ Vflat) {
    int m = blockIdx.x, t = threadIdx.x;  // 384
    __shared__ float sh[384];
    sh[t] = x12[(size_t)m * X12W + t];
    __syncthreads();
    int e = t / 3, c = t % 3;
    float acc = 0.f;
#pragma unroll 4
    for (int d = 0; d < 128; ++d)
        acc = fmaf(sh[d * 3 + c], W[d * 128 + e], acc);
    Vflat[(size_t)m * X12W + t] = acc;
}

// ---------------- Vflat[m, 384 + e*5+c] = sum_d x2[m,d,c] Wv2[d,e] ----------------
__global__ void v2_kernel(const float* __restrict__ x12, const float* __restrict__ W,
                          float* __restrict__ Vflat) {
    int m = blockIdx.x, t = threadIdx.x;  // 192, 160 active
    __shared__ float sh[160];
    if (t < 160) sh[t] = x12[(size_t)m * X12W + 384 + t];
    __syncthreads();
    if (t < 160) {
        int e = t / 5, c = t % 5;
        float acc = 0.f;
#pragma unroll 4
        for (int d = 0; d < 32; ++d)
            acc = fmaf(sh[d * 5 + c], W[d * 32 + e], acc);
        Vflat[(size_t)m * X12W + 384 + t] = acc;
    }
}

// ---------------- softmax rows of S in place + accumulate head-mean ----------------
template<bool INIT>
__global__ void softmax_am(float* __restrict__ S, float* __restrict__ am) {
    int n = blockIdx.x, t = threadIdx.x;  // 256 threads
    __shared__ float red[256];
    float* Sp = S + (size_t)n * N_;
    float s[8];
#pragma unroll
    for (int i = 0; i < 8; ++i) s[i] = Sp[i * 256 + t];
    float mx = s[0];
#pragma unroll
    for (int i = 1; i < 8; ++i) mx = fmaxf(mx, s[i]);
    red[t] = mx; __syncthreads();
    for (int st = 128; st > 0; st >>= 1) { if (t < st) red[t] = fmaxf(red[t], red[t + st]); __syncthreads(); }
    mx = red[0]; __syncthreads();
    float sum = 0.f;
#pragma unroll
    for (int i = 0; i < 8; ++i) { s[i] = expf(s[i] - mx); sum += s[i]; }
    red[t] = sum; __syncthreads();
    for (int st = 128; st > 0; st >>= 1) { if (t < st) red[t] += red[t + st]; __syncthreads(); }
    float rinv = 1.f / red[0];
#pragma unroll
    for (int i = 0; i < 8; ++i) {
        float pv = s[i] * rinv;
        Sp[i * 256 + t] = pv;
        float* amp = am + (size_t)n * N_ + i * 256 + t;
        *amp = INIT ? 0.25f * pv : *amp + 0.25f * pv;
    }
}

// ---------------- gating over x12 ----------------
__global__ void gate_kernel(const float* __restrict__ g, float* __restrict__ x12) {
    int idx = blockIdx.x * 256 + threadIdx.x;
    if (idx >= N_ * X12W) return;
    int n = idx / X12W, j = idx % X12W;
    float gv = (j < 384) ? g[n * 160 + j / 3] : g[n * 160 + 128 + (j - 384) / 5];
    x12[idx] *= gv;
}

extern "C" void kernel_launch(void* const* d_in, const int* in_sizes, int n_in,
                              void* d_out, int out_size, void* d_ws, size_t ws_size,
                              hipStream_t stream) {
    const float* x    = (const float*)d_in[0];
    const float* pos  = (const float*)d_in[1];
    const float* embW = (const float*)d_in[2];
    const float* embB = (const float*)d_in[3];
    const float* Wq   = (const float*)d_in[4];
    const float* Wk   = (const float*)d_in[5];
    const float* Wv0  = (const float*)d_in[6];
    const float* Wv1  = (const float*)d_in[7];
    const float* Wv2  = (const float*)d_in[8];
    const float* Ws1  = (const float*)d_in[9];
    const float* Ws2  = (const float*)d_in[10];
    const float* Wffa = (const float*)d_in[11];
    const float* Wffb = (const float*)d_in[12];
    const float* Wg   = (const float*)d_in[13];
    const float* outW = (const float*)d_in[14];
    const float* outB = (const float*)d_in[15];
    float* out = (float*)d_out;

    float* p = (float*)d_ws;
    float* x0    = p; p += N_ * D0_;
    float* x12   = p; p += N_ * X12W;
    float* inv   = p; p += N_ * F_;
    float* q     = p; p += N_ * D0_;
    float* k     = p; p += N_ * D0_;
    float* S     = p; p += (size_t)N_ * N_;
    float* am    = p; p += (size_t)N_ * N_;
    float* v0    = p; p += N_ * D0_;
    float* Vflat = p; p += N_ * X12W;
    float* s1    = p; p += N_ * D1_;
    float* s2    = p; p += N_ * D2_;
    float* fft   = p; p += N_ * 512;
    float* gm    = p; p += N_ * 160;
    u16*   U     = (u16*)p;                 // 3 * N * N bf16 = 24 MB

    hipMemsetAsync(x12, 0, (size_t)N_ * X12W * sizeof(float), stream);
    ucompute_kernel<<<(N_ * N_) / 256, 256, 0, stream>>>(pos, U);

    // embedding: x0 = x @ embW + embB   (K=118 -> guarded path)
    mfma_gemm<B_NN, EPI_STORE><<<dim3(4, 32), 256, 0, stream>>>(
        x, 118, embW, 256, embB, x0, 256, N_, 118, 256, 1.f, 118);

    for (int l = 0; l < L_; ++l) {
        const float* Wq_l   = Wq   + (size_t)l * F_ * 256;
        const float* Wk_l   = Wk   + (size_t)l * F_ * 256;
        const float* Wv0_l  = Wv0  + (size_t)l * 256 * 256;
        const float* Wv1_l  = Wv1  + (size_t)l * 128 * 128;
        const float* Wv2_l  = Wv2  + (size_t)l * 32 * 32;
        const float* Ws1_l  = Ws1  + (size_t)l * 256 * 128;
        const float* Ws2_l  = Ws2  + (size_t)l * 256 * 32;
        const float* Wffa_l = Wffa + (size_t)l * 256 * 512;
        const float* Wffb_l = Wffb + (size_t)l * 512 * 256;
        const float* Wg_l   = Wg   + (size_t)l * F_ * 160;

        invar_kernel<<<N_, 256, 0, stream>>>(x0, x12, inv);
        mfma_gemm<B_NN, EPI_STORE><<<dim3(4, 32), 256, 0, stream>>>(
            inv, F_, Wq_l, 256, nullptr, q, 256, N_, F_, 256, 1.f, F_);
        mfma_gemm<B_NN, EPI_STORE><<<dim3(4, 32), 256, 0, stream>>>(
            inv, F_, Wk_l, 256, nullptr, k, 256, N_, F_, 256, 1.f, F_);
        mfma_gemm<B_NN, EPI_STORE><<<dim3(4, 32), 256, 0, stream>>>(
            x0, 256, Wv0_l, 256, nullptr, v0, 256, N_, 256, 256, 1.f, 256);
        mfma_gemm<B_NN, EPI_STORE><<<dim3(2, 32), 256, 0, stream>>>(
            x0, 256, Ws1_l, 128, nullptr, s1, 128, N_, 256, 128, 1.f, 256);
        mfma_gemm<B_NN, EPI_STORE><<<dim3(1, 32), 256, 0, stream>>>(
            x0, 256, Ws2_l, 32, nullptr, s2, 32, N_, 256, 32, 1.f, 256);
        v1_kernel<<<N_, 384, 0, stream>>>(x12, Wv1_l, Vflat);
        v2_kernel<<<N_, 192, 0, stream>>>(x12, Wv2_l, Vflat);

        for (int h = 0; h < H_; ++h) {
            // S = (q_h @ k_h^T) / 8
            mfma_gemm<B_NT, EPI_STORE><<<dim3(32, 32), 256, 0, stream>>>(
                q + h * 64, 256, k + h * 64, 256, nullptr, S, N_, N_, 64, N_, 0.125f, 64);
            if (h == 0) softmax_am<true ><<<N_, 256, 0, stream>>>(S, am);
            else        softmax_am<false><<<N_, 256, 0, stream>>>(S, am);
            // x0[:, h*64:+64] += S @ v0[:, h*64:+64]   (split-K=8, atomic)
            mfma_gemm<B_NN, EPI_ATOMIC><<<dim3(1, 32, 8), 256, 0, stream>>>(
                S, N_, v0 + h * 64, 256, nullptr, x0 + h * 64, 256, N_, N_, 64, 1.f, 256);
        }

        // agg1+agg2: x12 += am @ Vflat
        mfma_gemm<B_NN, EPI_ACCUM><<<dim3(9, 32), 256, 0, stream>>>(
            am, N_, Vflat, X12W, nullptr, x12, X12W, N_, N_, X12W, 1.f, N_);
        // mix1+mix2: x12 += (am ⊙ Y_c) @ {s1|s2}
        mix_kernel<<<dim3(44, 32), 256, 0, stream>>>(am, U, s1, s2, x12);

        mfma_gemm<B_NN, EPI_SILU><<<dim3(8, 32), 256, 0, stream>>>(
            x0, 256, Wffa_l, 512, nullptr, fft, 512, N_, 256, 512, 1.f, 256);
        mfma_gemm<B_NN, EPI_ACCUM><<<dim3(4, 32), 256, 0, stream>>>(
            fft, 512, Wffb_l, 256, nullptr, x0, 256, N_, 512, 256, 1.f, 512);

        invar_kernel<<<N_, 256, 0, stream>>>(x0, x12, inv);
        mfma_gemm<B_NN, EPI_SIGMOID><<<dim3(3, 32), 256, 0, stream>>>(
            inv, F_, Wg_l, 160, nullptr, gm, 160, N_, F_, 160, 1.f, F_);
        gate_kernel<<<(N_ * X12W + 255) / 256, 256, 0, stream>>>(gm, x12);
    }

    mfma_gemm<B_NN, EPI_STORE><<<dim3(1, 32), 256, 0, stream>>>(
        x0, 256, outW, NC_, outB, out, NC_, N_, 256, NC_, 1.f, 256);
}

// Round 7
// 1765.961 us; speedup vs baseline: 5.3370x; 1.1471x over previous
//
#include <hip/hip_runtime.h>
#include <math.h>

#define N_    2048
#define D0_   256
#define D1_   128
#define D2_   32
#define F_    416
#define H_    4
#define DH_   64
#define L_    4
#define NC_   10
#define C2_   1.7320508075688772f
#define X12W  544   // x1 (128*3) | x2 (32*5) combined row width

typedef unsigned short u16;
typedef __attribute__((ext_vector_type(8))) short short8v;
typedef __attribute__((ext_vector_type(4))) float f32x4;

union U8 { u16 u[8]; short8v v; };

__device__ __forceinline__ u16 f2bf(float f) {
    union { float f; unsigned int u; } x; x.f = f;
    unsigned int r = x.u + 0x7FFFu + ((x.u >> 16) & 1u);
    return (u16)(r >> 16);
}
__device__ __forceinline__ float bf2f(u16 u) {
    union { float f; unsigned int u; } x; x.u = ((unsigned int)u) << 16;
    return x.f;
}

__device__ __forceinline__ f32x4 mfma16(short8v a, short8v b, f32x4 c) {
    return __builtin_amdgcn_mfma_f32_16x16x32_bf16(a, b, c, 0, 0, 0);
}

// ================= MFMA GEMM: f32 in (cast to bf16), epilogues ===========
enum { B_NN = 0, B_NT = 1 };
enum { EPI_STORE = 0, EPI_SILU = 1, EPI_SIGMOID = 2, EPI_ACCUM = 3, EPI_ATOMIC = 4,
       EPI_STOREB = 5 };  // store bf16 (C cast to u16*)

template<int BLAY, int EPI>
__global__ __launch_bounds__(256) void mfma_gemm(
    const float* __restrict__ A, int lda,
    const float* __restrict__ B, int ldb,
    const float* __restrict__ bias,
    float* __restrict__ C, int ldc,
    int M, int K, int Nn, float scale, int kchunk)
{
    __shared__ __align__(16) u16 As[64][40];
    __shared__ __align__(16) u16 Bs[64][40];
    const int t = threadIdx.x;
    const int bm = blockIdx.y * 64, bn = blockIdx.x * 64;
    const int lane = t & 63, w = t >> 6;
    const int r0 = (w >> 1) * 32, c0 = (w & 1) * 32;
    const int fr = lane & 15, fk = (lane >> 4) * 8;
    const int ml = t >> 2, k8 = (t & 3) * 8;
    const int kbeg = blockIdx.z * kchunk;
    const int kend = (kbeg + kchunk < K) ? kbeg + kchunk : K;
    f32x4 acc[2][2] = {};

    for (int k0 = kbeg; k0 < kend; k0 += 32) {
        {
            U8 u;
            if (((lda & 3) == 0) && (k0 + 32 <= kend)) {
                const float* ap = A + (size_t)(bm + ml) * lda + k0 + k8;
                float4 a0 = *(const float4*)ap;
                float4 a1 = *(const float4*)(ap + 4);
                u.u[0]=f2bf(a0.x); u.u[1]=f2bf(a0.y); u.u[2]=f2bf(a0.z); u.u[3]=f2bf(a0.w);
                u.u[4]=f2bf(a1.x); u.u[5]=f2bf(a1.y); u.u[6]=f2bf(a1.z); u.u[7]=f2bf(a1.w);
            } else {
#pragma unroll
                for (int j = 0; j < 8; ++j) {
                    int kk = k0 + k8 + j;
                    u.u[j] = f2bf(kk < kend ? A[(size_t)(bm + ml) * lda + kk] : 0.f);
                }
            }
            *(short8v*)&As[ml][k8] = u.v;
        }
        {
            U8 u;
            if (BLAY == B_NT) {
                if (((ldb & 3) == 0) && (k0 + 32 <= kend) && (bn + ml < Nn)) {
                    const float* bp = B + (size_t)(bn + ml) * ldb + k0 + k8;
                    float4 b0 = *(const float4*)bp;
                    float4 b1 = *(const float4*)(bp + 4);
                    u.u[0]=f2bf(b0.x); u.u[1]=f2bf(b0.y); u.u[2]=f2bf(b0.z); u.u[3]=f2bf(b0.w);
                    u.u[4]=f2bf(b1.x); u.u[5]=f2bf(b1.y); u.u[6]=f2bf(b1.z); u.u[7]=f2bf(b1.w);
                } else {
#pragma unroll
                    for (int j = 0; j < 8; ++j) {
                        int kk = k0 + k8 + j;
                        u.u[j] = f2bf((kk < kend && bn + ml < Nn)
                                      ? B[(size_t)(bn + ml) * ldb + kk] : 0.f);
                    }
                }
            } else {
                int nc = bn + ml;
#pragma unroll
                for (int j = 0; j < 8; ++j) {
                    int kk = k0 + k8 + j;
                    u.u[j] = f2bf((kk < kend && nc < Nn) ? B[(size_t)kk * ldb + nc] : 0.f);
                }
            }
            *(short8v*)&Bs[ml][k8] = u.v;
        }
        __syncthreads();
        short8v a0 = *(const short8v*)&As[r0 + fr][fk];
        short8v a1 = *(const short8v*)&As[r0 + 16 + fr][fk];
        short8v b0 = *(const short8v*)&Bs[c0 + fr][fk];
        short8v b1 = *(const short8v*)&Bs[c0 + 16 + fr][fk];
        acc[0][0] = mfma16(a0, b0, acc[0][0]);
        acc[0][1] = mfma16(a0, b1, acc[0][1]);
        acc[1][0] = mfma16(a1, b0, acc[1][0]);
        acc[1][1] = mfma16(a1, b1, acc[1][1]);
        __syncthreads();
    }
#pragma unroll
    for (int mi = 0; mi < 2; ++mi)
#pragma unroll
    for (int ni = 0; ni < 2; ++ni)
#pragma unroll
    for (int r = 0; r < 4; ++r) {
        int row = bm + r0 + mi * 16 + ((lane >> 4) << 2) + r;
        int col = bn + c0 + ni * 16 + fr;
        if (col >= Nn) continue;
        float v = acc[mi][ni][r];
        if (EPI == EPI_STOREB) {
            ((u16*)C)[(size_t)row * ldc + col] = f2bf(v * scale);
        } else {
            float* cp = C + (size_t)row * ldc + col;
            if (EPI == EPI_STORE)   *cp = v * scale + (bias ? bias[col] : 0.f);
            if (EPI == EPI_SILU)    *cp = v / (1.f + expf(-v));
            if (EPI == EPI_SIGMOID) *cp = 1.f / (1.f + expf(-v));
            if (EPI == EPI_ACCUM)   *cp += v;
            if (EPI == EPI_ATOMIC)  atomicAdd(cp, v);
        }
    }
}

// ============ aggP: bf16-A GEMM, NB column tiles, C = A@B (atomic) ============
template<int NB, int EPI>
__global__ __launch_bounds__(256) void aggP(
    const u16* __restrict__ A, int lda,
    const float* __restrict__ B, int ldb,
    float* __restrict__ C, int ldc,
    int K, int Nn, int kchunk)
{
    __shared__ __align__(16) u16 As[64][40];
    __shared__ __align__(16) u16 Bs[NB][64][40];
    const int t = threadIdx.x;
    const int bm = blockIdx.y * 64, bn0 = blockIdx.x * 64 * NB;
    const int lane = t & 63, w = t >> 6;
    const int r0 = (w >> 1) * 32, c0 = (w & 1) * 32;
    const int fr = lane & 15, fk = (lane >> 4) * 8;
    const int ml = t >> 2, k8 = (t & 3) * 8;
    const int kbeg = blockIdx.z * kchunk;
    const int kend = (kbeg + kchunk < K) ? kbeg + kchunk : K;
    f32x4 acc[NB][2][2] = {};

    for (int k0 = kbeg; k0 < kend; k0 += 32) {
        *(short8v*)&As[ml][k8] = *(const short8v*)(A + (size_t)(bm + ml) * lda + k0 + k8);
#pragma unroll
        for (int nb = 0; nb < NB; ++nb) {
            int nc = bn0 + nb * 64 + ml;
            U8 u;
#pragma unroll
            for (int j = 0; j < 8; ++j) {
                int kk = k0 + k8 + j;
                u.u[j] = f2bf(nc < Nn ? B[(size_t)kk * ldb + nc] : 0.f);
            }
            *(short8v*)&Bs[nb][ml][k8] = u.v;
        }
        __syncthreads();
        short8v a0 = *(const short8v*)&As[r0 + fr][fk];
        short8v a1 = *(const short8v*)&As[r0 + 16 + fr][fk];
#pragma unroll
        for (int nb = 0; nb < NB; ++nb) {
            short8v b0 = *(const short8v*)&Bs[nb][c0 + fr][fk];
            short8v b1 = *(const short8v*)&Bs[nb][c0 + 16 + fr][fk];
            acc[nb][0][0] = mfma16(a0, b0, acc[nb][0][0]);
            acc[nb][0][1] = mfma16(a0, b1, acc[nb][0][1]);
            acc[nb][1][0] = mfma16(a1, b0, acc[nb][1][0]);
            acc[nb][1][1] = mfma16(a1, b1, acc[nb][1][1]);
        }
        __syncthreads();
    }
#pragma unroll
    for (int nb = 0; nb < NB; ++nb)
#pragma unroll
    for (int mi = 0; mi < 2; ++mi)
#pragma unroll
    for (int ni = 0; ni < 2; ++ni)
#pragma unroll
    for (int r = 0; r < 4; ++r) {
        int row = bm + r0 + mi * 16 + ((lane >> 4) << 2) + r;
        int col = bn0 + nb * 64 + c0 + ni * 16 + fr;
        if (col >= Nn) continue;
        float v = acc[nb][mi][ni][r];
        float* cp = C + (size_t)row * ldc + col;
        if (EPI == EPI_ATOMIC) atomicAdd(cp, v);
        else                   *cp += v;
    }
}

// ---------------- u precompute: U[c][n][m] bf16 (24 MB) --------
__global__ void ucompute_kernel(const float* __restrict__ pos, u16* __restrict__ U) {
    int idx = blockIdx.x * 256 + threadIdx.x;
    int n = idx >> 11, m = idx & (N_ - 1);
    float rx = pos[m * 3 + 0] - pos[n * 3 + 0];
    float ry = pos[m * 3 + 1] - pos[n * 3 + 1];
    float rz = pos[m * 3 + 2] - pos[n * 3 + 2];
    float d2 = rx * rx + ry * ry + rz * rz;
    bool valid = d2 > 1e-12f;
    float rinv = valid ? rsqrtf(d2) : 0.f;
    size_t base = (size_t)n * N_ + m;
    const size_t CS = (size_t)N_ * N_;
    U[base]          = f2bf(rx * rinv);
    U[base + CS]     = f2bf(ry * rinv);
    U[base + 2 * CS] = f2bf(rz * rinv);
}

// ============ mix1: x12[:, d*3+c] += (am ⊙ u_c) @ s1, 3 channels/block ============
__global__ __launch_bounds__(256) void mix1_kernel(
    const u16* __restrict__ amb, const u16* __restrict__ U,
    const float* __restrict__ s1, float* __restrict__ x12)
{
    const int gx = blockIdx.x;
    const int colbase = (gx & 1) * 64, ks = gx >> 1;   // ks 0..3, kchunk 512
    const int bm = blockIdx.y * 64;
    const size_t CS = (size_t)N_ * N_;
    __shared__ __align__(16) u16 As[3][64][40];
    __shared__ __align__(16) u16 Bs[64][40];
    const int t = threadIdx.x, lane = t & 63, w = t >> 6;
    const int r0 = (w >> 1) * 32, c0 = (w & 1) * 32;
    const int fr = lane & 15, fk = (lane >> 4) * 8;
    const int ml = t >> 2, k8 = (t & 3) * 8;
    const int kbeg = ks * 512, kend = kbeg + 512;
    f32x4 acc[3][2][2] = {};

    for (int m0 = kbeg; m0 < kend; m0 += 32) {
        const size_t off = (size_t)(bm + ml) * N_ + m0 + k8;
        U8 am8; am8.v = *(const short8v*)(amb + off);
        U8 xv, yv, zv;
        xv.v = *(const short8v*)(U + off);
        yv.v = *(const short8v*)(U + CS + off);
        zv.v = *(const short8v*)(U + 2 * CS + off);
        U8 o0, o1, o2;
#pragma unroll
        for (int j = 0; j < 8; ++j) {
            float a = bf2f(am8.u[j]);
            o0.u[j] = f2bf(a * bf2f(xv.u[j]));
            o1.u[j] = f2bf(a * bf2f(yv.u[j]));
            o2.u[j] = f2bf(a * bf2f(zv.u[j]));
        }
        *(short8v*)&As[0][ml][k8] = o0.v;
        *(short8v*)&As[1][ml][k8] = o1.v;
        *(short8v*)&As[2][ml][k8] = o2.v;
        {
            int nc = colbase + ml;
            U8 u;
#pragma unroll
            for (int j = 0; j < 8; ++j)
                u.u[j] = f2bf(s1[(size_t)(m0 + k8 + j) * 128 + nc]);
            *(short8v*)&Bs[ml][k8] = u.v;
        }
        __syncthreads();
        short8v b0 = *(const short8v*)&Bs[c0 + fr][fk];
        short8v b1 = *(const short8v*)&Bs[c0 + 16 + fr][fk];
#pragma unroll
        for (int c = 0; c < 3; ++c) {
            short8v a0 = *(const short8v*)&As[c][r0 + fr][fk];
            short8v a1 = *(const short8v*)&As[c][r0 + 16 + fr][fk];
            acc[c][0][0] = mfma16(a0, b0, acc[c][0][0]);
            acc[c][0][1] = mfma16(a0, b1, acc[c][0][1]);
            acc[c][1][0] = mfma16(a1, b0, acc[c][1][0]);
            acc[c][1][1] = mfma16(a1, b1, acc[c][1][1]);
        }
        __syncthreads();
    }
#pragma unroll
    for (int c = 0; c < 3; ++c)
#pragma unroll
    for (int mi = 0; mi < 2; ++mi)
#pragma unroll
    for (int ni = 0; ni < 2; ++ni)
#pragma unroll
    for (int r = 0; r < 4; ++r) {
        int row = bm + r0 + mi * 16 + ((lane >> 4) << 2) + r;
        int col = colbase + c0 + ni * 16 + fr;
        atomicAdd(&x12[(size_t)row * X12W + col * 3 + c], acc[c][mi][ni][r]);
    }
}

// ============ mix2: x12[:, 384+d*5+c] += (am ⊙ Y2_c) @ s2, 5 channels/block ============
__global__ __launch_bounds__(256) void mix2_kernel(
    const u16* __restrict__ amb, const u16* __restrict__ U,
    const float* __restrict__ s2, float* __restrict__ x12)
{
    const int ks = blockIdx.x;                         // 0..7, kchunk 256
    const int bm = blockIdx.y * 64;
    const size_t CS = (size_t)N_ * N_;
    __shared__ __align__(16) u16 As[5][64][40];
    __shared__ __align__(16) u16 Bs[64][40];
    const int t = threadIdx.x, lane = t & 63, w = t >> 6;
    const int r0 = (w >> 1) * 32, c0 = (w & 1) * 32;
    const int fr = lane & 15, fk = (lane >> 4) * 8;
    const int ml = t >> 2, k8 = (t & 3) * 8;
    const int kbeg = ks * 256, kend = kbeg + 256;
    f32x4 acc[5][2][2] = {};

    for (int m0 = kbeg; m0 < kend; m0 += 32) {
        const size_t off = (size_t)(bm + ml) * N_ + m0 + k8;
        U8 am8; am8.v = *(const short8v*)(amb + off);
        U8 xv, yv, zv;
        xv.v = *(const short8v*)(U + off);
        yv.v = *(const short8v*)(U + CS + off);
        zv.v = *(const short8v*)(U + 2 * CS + off);
        U8 o[5];
#pragma unroll
        for (int j = 0; j < 8; ++j) {
            float a = bf2f(am8.u[j]);
            float ux = bf2f(xv.u[j]), uy = bf2f(yv.u[j]), uz = bf2f(zv.u[j]);
            o[0].u[j] = f2bf(a * C2_ * ux * uy);
            o[1].u[j] = f2bf(a * C2_ * uy * uz);
            o[2].u[j] = f2bf((ux*ux + uy*uy + uz*uz > 0.5f)
                             ? a * 0.5f * (3.f * uz * uz - 1.f) : 0.f);
            o[3].u[j] = f2bf(a * C2_ * ux * uz);
            o[4].u[j] = f2bf(a * 0.5f * C2_ * (ux * ux - uy * uy));
        }
#pragma unroll
        for (int c = 0; c < 5; ++c) *(short8v*)&As[c][ml][k8] = o[c].v;
        {
            int nc = ml;
            U8 u;
#pragma unroll
            for (int j = 0; j < 8; ++j)
                u.u[j] = f2bf(nc < 32 ? s2[(size_t)(m0 + k8 + j) * 32 + nc] : 0.f);
            *(short8v*)&Bs[ml][k8] = u.v;
        }
        __syncthreads();
        short8v b0 = *(const short8v*)&Bs[c0 + fr][fk];
        short8v b1 = *(const short8v*)&Bs[c0 + 16 + fr][fk];
#pragma unroll
        for (int c = 0; c < 5; ++c) {
            short8v a0 = *(const short8v*)&As[c][r0 + fr][fk];
            short8v a1 = *(const short8v*)&As[c][r0 + 16 + fr][fk];
            acc[c][0][0] = mfma16(a0, b0, acc[c][0][0]);
            acc[c][0][1] = mfma16(a0, b1, acc[c][0][1]);
            acc[c][1][0] = mfma16(a1, b0, acc[c][1][0]);
            acc[c][1][1] = mfma16(a1, b1, acc[c][1][1]);
        }
        __syncthreads();
    }
#pragma unroll
    for (int c = 0; c < 5; ++c)
#pragma unroll
    for (int mi = 0; mi < 2; ++mi)
#pragma unroll
    for (int ni = 0; ni < 2; ++ni)
#pragma unroll
    for (int r = 0; r < 4; ++r) {
        int row = bm + r0 + mi * 16 + ((lane >> 4) << 2) + r;
        int col = c0 + ni * 16 + fr;
        if (col < 32)
            atomicAdd(&x12[(size_t)row * X12W + 384 + col * 5 + c], acc[c][mi][ni][r]);
    }
}

// ---------------- invariants ----------------
__global__ void invar_kernel(const float* __restrict__ x0, const float* __restrict__ x12,
                             float* __restrict__ inv) {
    int n = blockIdx.x, t = threadIdx.x;
    inv[(size_t)n * F_ + t] = x0[(size_t)n * D0_ + t];
    if (t < 128) {
        const float* p = x12 + (size_t)n * X12W + t * 3;
        inv[(size_t)n * F_ + 256 + t] = sqrtf(p[0]*p[0] + p[1]*p[1] + p[2]*p[2]);
    }
    if (t < 32) {
        const float* p = x12 + (size_t)n * X12W + 384 + t * 5;
        inv[(size_t)n * F_ + 384 + t] =
            sqrtf(p[0]*p[0] + p[1]*p[1] + p[2]*p[2] + p[3]*p[3] + p[4]*p[4]);
    }
}

// ---------------- Vflat[m, e*3+c] = sum_d x1[m,d,c] Wv1[d,e] ----------------
__global__ void v1_kernel(const float* __restrict__ x12, const float* __restrict__ W,
                          float* __restrict__ Vflat) {
    int m = blockIdx.x, t = threadIdx.x;  // 384
    __shared__ float sh[384];
    sh[t] = x12[(size_t)m * X12W + t];
    __syncthreads();
    int e = t / 3, c = t % 3;
    float acc = 0.f;
#pragma unroll 4
    for (int d = 0; d < 128; ++d)
        acc = fmaf(sh[d * 3 + c], W[d * 128 + e], acc);
    Vflat[(size_t)m * X12W + t] = acc;
}

__global__ void v2_kernel(const float* __restrict__ x12, const float* __restrict__ W,
                          float* __restrict__ Vflat) {
    int m = blockIdx.x, t = threadIdx.x;  // 192, 160 active
    __shared__ float sh[160];
    if (t < 160) sh[t] = x12[(size_t)m * X12W + 384 + t];
    __syncthreads();
    if (t < 160) {
        int e = t / 5, c = t % 5;
        float acc = 0.f;
#pragma unroll 4
        for (int d = 0; d < 32; ++d)
            acc = fmaf(sh[d * 5 + c], W[d * 32 + e], acc);
        Vflat[(size_t)m * X12W + 384 + t] = acc;
    }
}

// ------- fused 4-head softmax: normalize P_h (bf16, in place) + write am bf16 -------
__global__ void softmax4(u16* __restrict__ Sb, u16* __restrict__ amb) {
    int n = blockIdx.x, t = threadIdx.x;  // 256 threads, 8 elems each
    __shared__ float red[256];
    const size_t NN = (size_t)N_ * N_;
    float amv[8] = {};
    for (int h = 0; h < H_; ++h) {
        u16* Sp = Sb + (size_t)h * NN + (size_t)n * N_ + t * 8;
        U8 sv; sv.v = *(const short8v*)Sp;
        float s[8];
#pragma unroll
        for (int j = 0; j < 8; ++j) s[j] = bf2f(sv.u[j]);
        float mx = s[0];
#pragma unroll
        for (int j = 1; j < 8; ++j) mx = fmaxf(mx, s[j]);
        red[t] = mx; __syncthreads();
        for (int st = 128; st > 0; st >>= 1) { if (t < st) red[t] = fmaxf(red[t], red[t + st]); __syncthreads(); }
        mx = red[0]; __syncthreads();
        float sum = 0.f;
#pragma unroll
        for (int j = 0; j < 8; ++j) { s[j] = expf(s[j] - mx); sum += s[j]; }
        red[t] = sum; __syncthreads();
        for (int st = 128; st > 0; st >>= 1) { if (t < st) red[t] += red[t + st]; __syncthreads(); }
        float rinv = 1.f / red[0]; __syncthreads();
        U8 pv;
#pragma unroll
        for (int j = 0; j < 8; ++j) {
            float p = s[j] * rinv;
            pv.u[j] = f2bf(p);
            amv[j] += 0.25f * p;
        }
        *(short8v*)Sp = pv.v;
    }
    U8 av;
#pragma unroll
    for (int j = 0; j < 8; ++j) av.u[j] = f2bf(amv[j]);
    *(short8v*)(amb + (size_t)n * N_ + t * 8) = av.v;
}

// ---------------- gating over x12 ----------------
__global__ void gate_kernel(const float* __restrict__ g, float* __restrict__ x12) {
    int idx = blockIdx.x * 256 + threadIdx.x;
    if (idx >= N_ * X12W) return;
    int n = idx / X12W, j = idx % X12W;
    float gv = (j < 384) ? g[n * 160 + j / 3] : g[n * 160 + 128 + (j - 384) / 5];
    x12[idx] *= gv;
}

extern "C" void kernel_launch(void* const* d_in, const int* in_sizes, int n_in,
                              void* d_out, int out_size, void* d_ws, size_t ws_size,
                              hipStream_t stream) {
    const float* x    = (const float*)d_in[0];
    const float* pos  = (const float*)d_in[1];
    const float* embW = (const float*)d_in[2];
    const float* embB = (const float*)d_in[3];
    const float* Wq   = (const float*)d_in[4];
    const float* Wk   = (const float*)d_in[5];
    const float* Wv0  = (const float*)d_in[6];
    const float* Wv1  = (const float*)d_in[7];
    const float* Wv2  = (const float*)d_in[8];
    const float* Ws1  = (const float*)d_in[9];
    const float* Ws2  = (const float*)d_in[10];
    const float* Wffa = (const float*)d_in[11];
    const float* Wffb = (const float*)d_in[12];
    const float* Wg   = (const float*)d_in[13];
    const float* outW = (const float*)d_in[14];
    const float* outB = (const float*)d_in[15];
    float* out = (float*)d_out;

    const size_t NN = (size_t)N_ * N_;
    float* p = (float*)d_ws;
    float* x0    = p; p += N_ * D0_;
    float* x12   = p; p += N_ * X12W;
    float* inv   = p; p += N_ * F_;
    float* q     = p; p += N_ * D0_;
    float* k     = p; p += N_ * D0_;
    float* v0    = p; p += N_ * D0_;
    float* Vflat = p; p += N_ * X12W;
    float* s1    = p; p += N_ * D1_;
    float* s2    = p; p += N_ * D2_;
    float* fft   = p; p += N_ * 512;
    float* gm    = p; p += N_ * 160;
    u16* ub  = (u16*)p;
    u16* Sb  = ub; ub += 4 * NN;   // 4 heads' S/P, bf16 (32 MB)
    u16* amb = ub; ub += NN;       // head-mean attention, bf16 (8 MB)
    u16* U   = ub;                 // unit vectors, 3 channels bf16 (24 MB)

    hipMemsetAsync(x12, 0, (size_t)N_ * X12W * sizeof(float), stream);
    ucompute_kernel<<<(N_ * N_) / 256, 256, 0, stream>>>(pos, U);

    mfma_gemm<B_NN, EPI_STORE><<<dim3(4, 32), 256, 0, stream>>>(
        x, 118, embW, 256, embB, x0, 256, N_, 118, 256, 1.f, 118);

    for (int l = 0; l < L_; ++l) {
        const float* Wq_l   = Wq   + (size_t)l * F_ * 256;
        const float* Wk_l   = Wk   + (size_t)l * F_ * 256;
        const float* Wv0_l  = Wv0  + (size_t)l * 256 * 256;
        const float* Wv1_l  = Wv1  + (size_t)l * 128 * 128;
        const float* Wv2_l  = Wv2  + (size_t)l * 32 * 32;
        const float* Ws1_l  = Ws1  + (size_t)l * 256 * 128;
        const float* Ws2_l  = Ws2  + (size_t)l * 256 * 32;
        const float* Wffa_l = Wffa + (size_t)l * 256 * 512;
        const float* Wffb_l = Wffb + (size_t)l * 512 * 256;
        const float* Wg_l   = Wg   + (size_t)l * F_ * 160;

        invar_kernel<<<N_, 256, 0, stream>>>(x0, x12, inv);
        mfma_gemm<B_NN, EPI_STORE><<<dim3(4, 32), 256, 0, stream>>>(
            inv, F_, Wq_l, 256, nullptr, q, 256, N_, F_, 256, 1.f, F_);
        mfma_gemm<B_NN, EPI_STORE><<<dim3(4, 32), 256, 0, stream>>>(
            inv, F_, Wk_l, 256, nullptr, k, 256, N_, F_, 256, 1.f, F_);
        mfma_gemm<B_NN, EPI_STORE><<<dim3(4, 32), 256, 0, stream>>>(
            x0, 256, Wv0_l, 256, nullptr, v0, 256, N_, 256, 256, 1.f, 256);
        mfma_gemm<B_NN, EPI_STORE><<<dim3(2, 32), 256, 0, stream>>>(
            x0, 256, Ws1_l, 128, nullptr, s1, 128, N_, 256, 128, 1.f, 256);
        mfma_gemm<B_NN, EPI_STORE><<<dim3(1, 32), 256, 0, stream>>>(
            x0, 256, Ws2_l, 32, nullptr, s2, 32, N_, 256, 32, 1.f, 256);
        v1_kernel<<<N_, 384, 0, stream>>>(x12, Wv1_l, Vflat);
        v2_kernel<<<N_, 192, 0, stream>>>(x12, Wv2_l, Vflat);

        // S_h = (q_h @ k_h^T)/8 -> bf16
        for (int h = 0; h < H_; ++h)
            mfma_gemm<B_NT, EPI_STOREB><<<dim3(32, 32), 256, 0, stream>>>(
                q + h * 64, 256, k + h * 64, 256, nullptr,
                (float*)(Sb + (size_t)h * NN), N_, N_, 64, N_, 0.125f, 64);
        // normalize all heads in place + emit am (bf16)
        softmax4<<<N_, 256, 0, stream>>>(Sb, amb);
        // x0[:, h*64:+64] += P_h @ v0_h  (split-K=8, atomic)
        for (int h = 0; h < H_; ++h)
            aggP<1, EPI_ATOMIC><<<dim3(1, 32, 8), 256, 0, stream>>>(
                Sb + (size_t)h * NN, N_, v0 + h * 64, 256, x0 + h * 64, 256,
                N_, 64, 256);

        // agg1+agg2: x12 += am @ Vflat  (3 col-tiles/block, split-K=3, atomic)
        aggP<3, EPI_ATOMIC><<<dim3(3, 32, 3), 256, 0, stream>>>(
            amb, N_, Vflat, X12W, x12, X12W, N_, X12W, 704);
        // mix terms
        mix1_kernel<<<dim3(8, 32), 256, 0, stream>>>(amb, U, s1, x12);
        mix2_kernel<<<dim3(8, 32), 256, 0, stream>>>(amb, U, s2, x12);

        mfma_gemm<B_NN, EPI_SILU><<<dim3(8, 32), 256, 0, stream>>>(
            x0, 256, Wffa_l, 512, nullptr, fft, 512, N_, 256, 512, 1.f, 256);
        mfma_gemm<B_NN, EPI_ACCUM><<<dim3(4, 32), 256, 0, stream>>>(
            fft, 512, Wffb_l, 256, nullptr, x0, 256, N_, 512, 256, 1.f, 512);

        invar_kernel<<<N_, 256, 0, stream>>>(x0, x12, inv);
        mfma_gemm<B_NN, EPI_SIGMOID><<<dim3(3, 32), 256, 0, stream>>>(
            inv, F_, Wg_l, 160, nullptr, gm, 160, N_, F_, 160, 1.f, F_);
        gate_kernel<<<(N_ * X12W + 255) / 256, 256, 0, stream>>>(gm, x12);
    }

    mfma_gemm<B_NN, EPI_STORE><<<dim3(1, 32), 256, 0, stream>>>(
        x0, 256, outW, NC_, outB, out, NC_, N_, 256, NC_, 1.f, 256);
}

// Round 8
// 1569.031 us; speedup vs baseline: 6.0069x; 1.1255x over previous
//
#include <hip/hip_runtime.h>
#include <math.h>

#define N_    2048
#define D0_   256
#define D1_   128
#define D2_   32
#define F_    416
#define H_    4
#define DH_   64
#define L_    4
#define NC_   10
#define C2_   1.7320508075688772f
#define X12W  544   // x1 (128*3) | x2 (32*5) combined row width

typedef unsigned short u16;
typedef __attribute__((ext_vector_type(8))) short short8v;
typedef __attribute__((ext_vector_type(4))) float f32x4;

union U8 { u16 u[8]; short8v v; };

__device__ __forceinline__ u16 f2bf(float f) {
    union { float f; unsigned int u; } x; x.f = f;
    unsigned int r = x.u + 0x7FFFu + ((x.u >> 16) & 1u);
    return (u16)(r >> 16);
}
__device__ __forceinline__ float bf2f(u16 u) {
    union { float f; unsigned int u; } x; x.u = ((unsigned int)u) << 16;
    return x.f;
}

__device__ __forceinline__ f32x4 mfma16(short8v a, short8v b, f32x4 c) {
    return __builtin_amdgcn_mfma_f32_16x16x32_bf16(a, b, c, 0, 0, 0);
}

// ================= MFMA GEMM: f32 in (cast to bf16), epilogues ===========
// blockIdx.z = h*zk + kz : h = head (A+=h*Ah, B+=h*Bh, C+=h*Ch), kz = K-split.
enum { B_NN = 0, B_NT = 1 };
enum { EPI_STORE = 0, EPI_SILU = 1, EPI_SIGMOID = 2, EPI_ACCUM = 3, EPI_ATOMIC = 4,
       EPI_STOREB = 5 };  // store bf16 (C cast to u16*)

template<int BLAY, int EPI>
__global__ __launch_bounds__(256) void mfma_gemm(
    const float* __restrict__ A, int lda,
    const float* __restrict__ B, int ldb,
    const float* __restrict__ bias,
    float* __restrict__ C, int ldc,
    int M, int K, int Nn, float scale, int kchunk,
    int zk, long long Ah, long long Bh, long long Ch)
{
    __shared__ __align__(16) u16 As[64][40];
    __shared__ __align__(16) u16 Bs[64][40];
    const int t = threadIdx.x;
    const int bm = blockIdx.y * 64, bn = blockIdx.x * 64;
    const int hz = blockIdx.z / zk, kz = blockIdx.z % zk;
    A += (size_t)hz * Ah; B += (size_t)hz * Bh;
    const int lane = t & 63, w = t >> 6;
    const int r0 = (w >> 1) * 32, c0 = (w & 1) * 32;
    const int fr = lane & 15, fk = (lane >> 4) * 8;
    const int ml = t >> 2, k8 = (t & 3) * 8;
    const int kbeg = kz * kchunk;
    const int kend = (kbeg + kchunk < K) ? kbeg + kchunk : K;
    f32x4 acc[2][2] = {};

    for (int k0 = kbeg; k0 < kend; k0 += 32) {
        {
            U8 u;
            if (((lda & 3) == 0) && (k0 + 32 <= kend)) {
                const float* ap = A + (size_t)(bm + ml) * lda + k0 + k8;
                float4 a0 = *(const float4*)ap;
                float4 a1 = *(const float4*)(ap + 4);
                u.u[0]=f2bf(a0.x); u.u[1]=f2bf(a0.y); u.u[2]=f2bf(a0.z); u.u[3]=f2bf(a0.w);
                u.u[4]=f2bf(a1.x); u.u[5]=f2bf(a1.y); u.u[6]=f2bf(a1.z); u.u[7]=f2bf(a1.w);
            } else {
#pragma unroll
                for (int j = 0; j < 8; ++j) {
                    int kk = k0 + k8 + j;
                    u.u[j] = f2bf(kk < kend ? A[(size_t)(bm + ml) * lda + kk] : 0.f);
                }
            }
            *(short8v*)&As[ml][k8] = u.v;
        }
        {
            U8 u;
            if (BLAY == B_NT) {
                if (((ldb & 3) == 0) && (k0 + 32 <= kend) && (bn + ml < Nn)) {
                    const float* bp = B + (size_t)(bn + ml) * ldb + k0 + k8;
                    float4 b0 = *(const float4*)bp;
                    float4 b1 = *(const float4*)(bp + 4);
                    u.u[0]=f2bf(b0.x); u.u[1]=f2bf(b0.y); u.u[2]=f2bf(b0.z); u.u[3]=f2bf(b0.w);
                    u.u[4]=f2bf(b1.x); u.u[5]=f2bf(b1.y); u.u[6]=f2bf(b1.z); u.u[7]=f2bf(b1.w);
                } else {
#pragma unroll
                    for (int j = 0; j < 8; ++j) {
                        int kk = k0 + k8 + j;
                        u.u[j] = f2bf((kk < kend && bn + ml < Nn)
                                      ? B[(size_t)(bn + ml) * ldb + kk] : 0.f);
                    }
                }
            } else {
                int nc = bn + ml;
#pragma unroll
                for (int j = 0; j < 8; ++j) {
                    int kk = k0 + k8 + j;
                    u.u[j] = f2bf((kk < kend && nc < Nn) ? B[(size_t)kk * ldb + nc] : 0.f);
                }
            }
            *(short8v*)&Bs[ml][k8] = u.v;
        }
        __syncthreads();
        short8v a0 = *(const short8v*)&As[r0 + fr][fk];
        short8v a1 = *(const short8v*)&As[r0 + 16 + fr][fk];
        short8v b0 = *(const short8v*)&Bs[c0 + fr][fk];
        short8v b1 = *(const short8v*)&Bs[c0 + 16 + fr][fk];
        acc[0][0] = mfma16(a0, b0, acc[0][0]);
        acc[0][1] = mfma16(a0, b1, acc[0][1]);
        acc[1][0] = mfma16(a1, b0, acc[1][0]);
        acc[1][1] = mfma16(a1, b1, acc[1][1]);
        __syncthreads();
    }
#pragma unroll
    for (int mi = 0; mi < 2; ++mi)
#pragma unroll
    for (int ni = 0; ni < 2; ++ni)
#pragma unroll
    for (int r = 0; r < 4; ++r) {
        int row = bm + r0 + mi * 16 + ((lane >> 4) << 2) + r;
        int col = bn + c0 + ni * 16 + fr;
        if (col >= Nn) continue;
        float v = acc[mi][ni][r];
        if (EPI == EPI_STOREB) {
            ((u16*)C + (size_t)hz * Ch)[(size_t)row * ldc + col] = f2bf(v * scale);
        } else {
            float* cp = C + (size_t)hz * Ch + (size_t)row * ldc + col;
            if (EPI == EPI_STORE)   *cp = v * scale + (bias ? bias[col] : 0.f);
            if (EPI == EPI_SILU)    *cp = v / (1.f + expf(-v));
            if (EPI == EPI_SIGMOID) *cp = 1.f / (1.f + expf(-v));
            if (EPI == EPI_ACCUM)   *cp += v;
            if (EPI == EPI_ATOMIC)  atomicAdd(cp, v);
        }
    }
}

// ============ aggP: bf16-A GEMM, NB column tiles, atomic; z = h*zk + kz ============
template<int NB, int EPI>
__global__ __launch_bounds__(256) void aggP(
    const u16* __restrict__ A, int lda,
    const float* __restrict__ B, int ldb,
    float* __restrict__ C, int ldc,
    int K, int Nn, int kchunk,
    int zk, long long Ah, long long Bh, long long Ch)
{
    __shared__ __align__(16) u16 As[64][40];
    __shared__ __align__(16) u16 Bs[NB][64][40];
    const int t = threadIdx.x;
    const int bm = blockIdx.y * 64, bn0 = blockIdx.x * 64 * NB;
    const int hz = blockIdx.z / zk, kz = blockIdx.z % zk;
    A += (size_t)hz * Ah; B += (size_t)hz * Bh; C += (size_t)hz * Ch;
    const int lane = t & 63, w = t >> 6;
    const int r0 = (w >> 1) * 32, c0 = (w & 1) * 32;
    const int fr = lane & 15, fk = (lane >> 4) * 8;
    const int ml = t >> 2, k8 = (t & 3) * 8;
    const int kbeg = kz * kchunk;
    const int kend = (kbeg + kchunk < K) ? kbeg + kchunk : K;
    f32x4 acc[NB][2][2] = {};

    for (int k0 = kbeg; k0 < kend; k0 += 32) {
        *(short8v*)&As[ml][k8] = *(const short8v*)(A + (size_t)(bm + ml) * lda + k0 + k8);
#pragma unroll
        for (int nb = 0; nb < NB; ++nb) {
            int nc = bn0 + nb * 64 + ml;
            U8 u;
#pragma unroll
            for (int j = 0; j < 8; ++j) {
                int kk = k0 + k8 + j;
                u.u[j] = f2bf(nc < Nn ? B[(size_t)kk * ldb + nc] : 0.f);
            }
            *(short8v*)&Bs[nb][ml][k8] = u.v;
        }
        __syncthreads();
        short8v a0 = *(const short8v*)&As[r0 + fr][fk];
        short8v a1 = *(const short8v*)&As[r0 + 16 + fr][fk];
#pragma unroll
        for (int nb = 0; nb < NB; ++nb) {
            short8v b0 = *(const short8v*)&Bs[nb][c0 + fr][fk];
            short8v b1 = *(const short8v*)&Bs[nb][c0 + 16 + fr][fk];
            acc[nb][0][0] = mfma16(a0, b0, acc[nb][0][0]);
            acc[nb][0][1] = mfma16(a0, b1, acc[nb][0][1]);
            acc[nb][1][0] = mfma16(a1, b0, acc[nb][1][0]);
            acc[nb][1][1] = mfma16(a1, b1, acc[nb][1][1]);
        }
        __syncthreads();
    }
#pragma unroll
    for (int nb = 0; nb < NB; ++nb)
#pragma unroll
    for (int mi = 0; mi < 2; ++mi)
#pragma unroll
    for (int ni = 0; ni < 2; ++ni)
#pragma unroll
    for (int r = 0; r < 4; ++r) {
        int row = bm + r0 + mi * 16 + ((lane >> 4) << 2) + r;
        int col = bn0 + nb * 64 + c0 + ni * 16 + fr;
        if (col >= Nn) continue;
        float v = acc[nb][mi][ni][r];
        float* cp = C + (size_t)row * ldc + col;
        if (EPI == EPI_ATOMIC) atomicAdd(cp, v);
        else                   *cp += v;
    }
}

// ---------------- u precompute: U[c][n][m] bf16 (24 MB) --------
__global__ void ucompute_kernel(const float* __restrict__ pos, u16* __restrict__ U) {
    int idx = blockIdx.x * 256 + threadIdx.x;
    int n = idx >> 11, m = idx & (N_ - 1);
    float rx = pos[m * 3 + 0] - pos[n * 3 + 0];
    float ry = pos[m * 3 + 1] - pos[n * 3 + 1];
    float rz = pos[m * 3 + 2] - pos[n * 3 + 2];
    float d2 = rx * rx + ry * ry + rz * rz;
    bool valid = d2 > 1e-12f;
    float rinv = valid ? rsqrtf(d2) : 0.f;
    size_t base = (size_t)n * N_ + m;
    const size_t CS = (size_t)N_ * N_;
    U[base]          = f2bf(rx * rinv);
    U[base + CS]     = f2bf(ry * rinv);
    U[base + 2 * CS] = f2bf(rz * rinv);
}

// ============ mixc: one Y-channel per block; x12 += (am ⊙ Y_c) @ {s1|s2} ============
// grid (8, 32, 8): z = channel (0-2 deg1, 3-7 deg2);
//   deg1: x = coltile(2) * ks(4), kchunk 512;  deg2: x = ks(8), kchunk 256.
__global__ __launch_bounds__(256) void mixc_kernel(
    const u16* __restrict__ amb, const u16* __restrict__ U,
    const float* __restrict__ s1, const float* __restrict__ s2,
    float* __restrict__ x12)
{
    const int ch = blockIdx.z;
    const int gx = blockIdx.x;
    const int bm = blockIdx.y * 64;
    const size_t CS = (size_t)N_ * N_;
    const bool deg1 = ch < 3;
    const int colbase = deg1 ? (gx & 1) * 64 : 0;
    const int ks      = deg1 ? (gx >> 1) : gx;
    const int kchunk  = deg1 ? 512 : 256;
    const float* Bp   = deg1 ? s1 : s2;
    const int Bld     = deg1 ? 128 : 32;
    __shared__ __align__(16) u16 As[64][40];
    __shared__ __align__(16) u16 Bs[64][40];
    const int t = threadIdx.x, lane = t & 63, w = t >> 6;
    const int r0 = (w >> 1) * 32, c0 = (w & 1) * 32;
    const int fr = lane & 15, fk = (lane >> 4) * 8;
    const int ml = t >> 2, k8 = (t & 3) * 8;
    const int kbeg = ks * kchunk, kend = kbeg + kchunk;
    f32x4 acc[2][2] = {};

    for (int m0 = kbeg; m0 < kend; m0 += 32) {
        const size_t off = (size_t)(bm + ml) * N_ + m0 + k8;
        U8 am8; am8.v = *(const short8v*)(amb + off);
        U8 o;
        if (deg1) {
            U8 uv; uv.v = *(const short8v*)(U + (size_t)ch * CS + off);
#pragma unroll
            for (int j = 0; j < 8; ++j)
                o.u[j] = f2bf(bf2f(am8.u[j]) * bf2f(uv.u[j]));
        } else {
            U8 xv, yv, zv;
            xv.v = *(const short8v*)(U + off);
            yv.v = *(const short8v*)(U + CS + off);
            zv.v = *(const short8v*)(U + 2 * CS + off);
#pragma unroll
            for (int j = 0; j < 8; ++j) {
                float a = bf2f(am8.u[j]);
                float ux = bf2f(xv.u[j]), uy = bf2f(yv.u[j]), uz = bf2f(zv.u[j]);
                float y;
                if      (ch == 3) y = C2_ * ux * uy;
                else if (ch == 4) y = C2_ * uy * uz;
                else if (ch == 5) y = (ux*ux + uy*uy + uz*uz > 0.5f)
                                      ? 0.5f * (3.f * uz * uz - 1.f) : 0.f;
                else if (ch == 6) y = C2_ * ux * uz;
                else              y = 0.5f * C2_ * (ux * ux - uy * uy);
                o.u[j] = f2bf(a * y);
            }
        }
        *(short8v*)&As[ml][k8] = o.v;
        {
            int nc = colbase + ml;
            U8 u;
#pragma unroll
            for (int j = 0; j < 8; ++j)
                u.u[j] = f2bf((deg1 || nc < 32)
                              ? Bp[(size_t)(m0 + k8 + j) * Bld + nc] : 0.f);
            *(short8v*)&Bs[ml][k8] = u.v;
        }
        __syncthreads();
        short8v a0 = *(const short8v*)&As[r0 + fr][fk];
        short8v a1 = *(const short8v*)&As[r0 + 16 + fr][fk];
        short8v b0 = *(const short8v*)&Bs[c0 + fr][fk];
        short8v b1 = *(const short8v*)&Bs[c0 + 16 + fr][fk];
        acc[0][0] = mfma16(a0, b0, acc[0][0]);
        acc[0][1] = mfma16(a0, b1, acc[0][1]);
        acc[1][0] = mfma16(a1, b0, acc[1][0]);
        acc[1][1] = mfma16(a1, b1, acc[1][1]);
        __syncthreads();
    }
#pragma unroll
    for (int mi = 0; mi < 2; ++mi)
#pragma unroll
    for (int ni = 0; ni < 2; ++ni)
#pragma unroll
    for (int r = 0; r < 4; ++r) {
        int row = bm + r0 + mi * 16 + ((lane >> 4) << 2) + r;
        int col = colbase + c0 + ni * 16 + fr;
        float v = acc[mi][ni][r];
        if (deg1)          atomicAdd(&x12[(size_t)row * X12W + col * 3 + ch], v);
        else if (col < 32) atomicAdd(&x12[(size_t)row * X12W + 384 + col * 5 + (ch - 3)], v);
    }
}

// ---------------- invariants ----------------
__global__ void invar_kernel(const float* __restrict__ x0, const float* __restrict__ x12,
                             float* __restrict__ inv) {
    int n = blockIdx.x, t = threadIdx.x;
    inv[(size_t)n * F_ + t] = x0[(size_t)n * D0_ + t];
    if (t < 128) {
        const float* p = x12 + (size_t)n * X12W + t * 3;
        inv[(size_t)n * F_ + 256 + t] = sqrtf(p[0]*p[0] + p[1]*p[1] + p[2]*p[2]);
    }
    if (t < 32) {
        const float* p = x12 + (size_t)n * X12W + 384 + t * 5;
        inv[(size_t)n * F_ + 384 + t] =
            sqrtf(p[0]*p[0] + p[1]*p[1] + p[2]*p[2] + p[3]*p[3] + p[4]*p[4]);
    }
}

// ---------------- Vflat[m, e*3+c] = sum_d x1[m,d,c] Wv1[d,e] ----------------
__global__ void v1_kernel(const float* __restrict__ x12, const float* __restrict__ W,
                          float* __restrict__ Vflat) {
    int m = blockIdx.x, t = threadIdx.x;  // 384
    __shared__ float sh[384];
    sh[t] = x12[(size_t)m * X12W + t];
    __syncthreads();
    int e = t / 3, c = t % 3;
    float acc = 0.f;
#pragma unroll 4
    for (int d = 0; d < 128; ++d)
        acc = fmaf(sh[d * 3 + c], W[d * 128 + e], acc);
    Vflat[(size_t)m * X12W + t] = acc;
}

__global__ void v2_kernel(const float* __restrict__ x12, const float* __restrict__ W,
                          float* __restrict__ Vflat) {
    int m = blockIdx.x, t = threadIdx.x;  // 192, 160 active
    __shared__ float sh[160];
    if (t < 160) sh[t] = x12[(size_t)m * X12W + 384 + t];
    __syncthreads();
    if (t < 160) {
        int e = t / 5, c = t % 5;
        float acc = 0.f;
#pragma unroll 4
        for (int d = 0; d < 32; ++d)
            acc = fmaf(sh[d * 5 + c], W[d * 32 + e], acc);
        Vflat[(size_t)m * X12W + 384 + t] = acc;
    }
}

// ------- fused 4-head softmax: normalize P_h (bf16, in place) + write am bf16 -------
__global__ void softmax4(u16* __restrict__ Sb, u16* __restrict__ amb) {
    int n = blockIdx.x, t = threadIdx.x;  // 256 threads, 8 elems each
    __shared__ float red[256];
    const size_t NN = (size_t)N_ * N_;
    float amv[8] = {};
    for (int h = 0; h < H_; ++h) {
        u16* Sp = Sb + (size_t)h * NN + (size_t)n * N_ + t * 8;
        U8 sv; sv.v = *(const short8v*)Sp;
        float s[8];
#pragma unroll
        for (int j = 0; j < 8; ++j) s[j] = bf2f(sv.u[j]);
        float mx = s[0];
#pragma unroll
        for (int j = 1; j < 8; ++j) mx = fmaxf(mx, s[j]);
        red[t] = mx; __syncthreads();
        for (int st = 128; st > 0; st >>= 1) { if (t < st) red[t] = fmaxf(red[t], red[t + st]); __syncthreads(); }
        mx = red[0]; __syncthreads();
        float sum = 0.f;
#pragma unroll
        for (int j = 0; j < 8; ++j) { s[j] = expf(s[j] - mx); sum += s[j]; }
        red[t] = sum; __syncthreads();
        for (int st = 128; st > 0; st >>= 1) { if (t < st) red[t] += red[t + st]; __syncthreads(); }
        float rinv = 1.f / red[0]; __syncthreads();
        U8 pv;
#pragma unroll
        for (int j = 0; j < 8; ++j) {
            float p = s[j] * rinv;
            pv.u[j] = f2bf(p);
            amv[j] += 0.25f * p;
        }
        *(short8v*)Sp = pv.v;
    }
    U8 av;
#pragma unroll
    for (int j = 0; j < 8; ++j) av.u[j] = f2bf(amv[j]);
    *(short8v*)(amb + (size_t)n * N_ + t * 8) = av.v;
}

// ---------------- gating over x12 ----------------
__global__ void gate_kernel(const float* __restrict__ g, float* __restrict__ x12) {
    int idx = blockIdx.x * 256 + threadIdx.x;
    if (idx >= N_ * X12W) return;
    int n = idx / X12W, j = idx % X12W;
    float gv = (j < 384) ? g[n * 160 + j / 3] : g[n * 160 + 128 + (j - 384) / 5];
    x12[idx] *= gv;
}

extern "C" void kernel_launch(void* const* d_in, const int* in_sizes, int n_in,
                              void* d_out, int out_size, void* d_ws, size_t ws_size,
                              hipStream_t stream) {
    const float* x    = (const float*)d_in[0];
    const float* pos  = (const float*)d_in[1];
    const float* embW = (const float*)d_in[2];
    const float* embB = (const float*)d_in[3];
    const float* Wq   = (const float*)d_in[4];
    const float* Wk   = (const float*)d_in[5];
    const float* Wv0  = (const float*)d_in[6];
    const float* Wv1  = (const float*)d_in[7];
    const float* Wv2  = (const float*)d_in[8];
    const float* Ws1  = (const float*)d_in[9];
    const float* Ws2  = (const float*)d_in[10];
    const float* Wffa = (const float*)d_in[11];
    const float* Wffb = (const float*)d_in[12];
    const float* Wg   = (const float*)d_in[13];
    const float* outW = (const float*)d_in[14];
    const float* outB = (const float*)d_in[15];
    float* out = (float*)d_out;

    const size_t NN = (size_t)N_ * N_;
    float* p = (float*)d_ws;
    float* x0    = p; p += N_ * D0_;
    float* x12   = p; p += N_ * X12W;
    float* inv   = p; p += N_ * F_;
    float* q     = p; p += N_ * D0_;
    float* k     = p; p += N_ * D0_;
    float* v0    = p; p += N_ * D0_;
    float* Vflat = p; p += N_ * X12W;
    float* s1    = p; p += N_ * D1_;
    float* s2    = p; p += N_ * D2_;
    float* fft   = p; p += N_ * 512;
    float* gm    = p; p += N_ * 160;
    u16* ub  = (u16*)p;
    u16* Sb  = ub; ub += 4 * NN;   // 4 heads' S/P, bf16 (32 MB)
    u16* amb = ub; ub += NN;       // head-mean attention, bf16 (8 MB)
    u16* U   = ub;                 // unit vectors, 3 channels bf16 (24 MB)

    hipMemsetAsync(x12, 0, (size_t)N_ * X12W * sizeof(float), stream);
    ucompute_kernel<<<(N_ * N_) / 256, 256, 0, stream>>>(pos, U);

    mfma_gemm<B_NN, EPI_STORE><<<dim3(4, 32), 256, 0, stream>>>(
        x, 118, embW, 256, embB, x0, 256, N_, 118, 256, 1.f, 118, 1, 0, 0, 0);

    for (int l = 0; l < L_; ++l) {
        const float* Wq_l   = Wq   + (size_t)l * F_ * 256;
        const float* Wk_l   = Wk   + (size_t)l * F_ * 256;
        const float* Wv0_l  = Wv0  + (size_t)l * 256 * 256;
        const float* Wv1_l  = Wv1  + (size_t)l * 128 * 128;
        const float* Wv2_l  = Wv2  + (size_t)l * 32 * 32;
        const float* Ws1_l  = Ws1  + (size_t)l * 256 * 128;
        const float* Ws2_l  = Ws2  + (size_t)l * 256 * 32;
        const float* Wffa_l = Wffa + (size_t)l * 256 * 512;
        const float* Wffb_l = Wffb + (size_t)l * 512 * 256;
        const float* Wg_l   = Wg   + (size_t)l * F_ * 160;

        invar_kernel<<<N_, 256, 0, stream>>>(x0, x12, inv);
        mfma_gemm<B_NN, EPI_STORE><<<dim3(4, 32), 256, 0, stream>>>(
            inv, F_, Wq_l, 256, nullptr, q, 256, N_, F_, 256, 1.f, F_, 1, 0, 0, 0);
        mfma_gemm<B_NN, EPI_STORE><<<dim3(4, 32), 256, 0, stream>>>(
            inv, F_, Wk_l, 256, nullptr, k, 256, N_, F_, 256, 1.f, F_, 1, 0, 0, 0);
        mfma_gemm<B_NN, EPI_STORE><<<dim3(4, 32), 256, 0, stream>>>(
            x0, 256, Wv0_l, 256, nullptr, v0, 256, N_, 256, 256, 1.f, 256, 1, 0, 0, 0);
        mfma_gemm<B_NN, EPI_STORE><<<dim3(2, 32), 256, 0, stream>>>(
            x0, 256, Ws1_l, 128, nullptr, s1, 128, N_, 256, 128, 1.f, 256, 1, 0, 0, 0);
        mfma_gemm<B_NN, EPI_STORE><<<dim3(1, 32), 256, 0, stream>>>(
            x0, 256, Ws2_l, 32, nullptr, s2, 32, N_, 256, 32, 1.f, 256, 1, 0, 0, 0);
        v1_kernel<<<N_, 384, 0, stream>>>(x12, Wv1_l, Vflat);
        v2_kernel<<<N_, 192, 0, stream>>>(x12, Wv2_l, Vflat);

        // S_h = (q_h @ k_h^T)/8 -> bf16, all 4 heads in one launch (z = head)
        mfma_gemm<B_NT, EPI_STOREB><<<dim3(32, 32, 4), 256, 0, stream>>>(
            q, 256, k, 256, nullptr, (float*)Sb, N_, N_, 64, N_, 0.125f, 64,
            1, 64, 64, (long long)NN);
        softmax4<<<N_, 256, 0, stream>>>(Sb, amb);
        // x0[:, h*64:+64] += P_h @ v0_h : all heads, split-K=8 (z = h*8+ks)
        aggP<1, EPI_ATOMIC><<<dim3(1, 32, 32), 256, 0, stream>>>(
            Sb, N_, v0, 256, x0, 256, N_, 64, 256,
            8, (long long)NN, 64, 64);

        // agg1+agg2: x12 += am @ Vflat  (3 col-tiles/block, split-K=4)
        aggP<3, EPI_ATOMIC><<<dim3(3, 32, 4), 256, 0, stream>>>(
            amb, N_, Vflat, X12W, x12, X12W, N_, X12W, 512,
            4, 0, 0, 0);
        // mix: one channel per block
        mixc_kernel<<<dim3(8, 32, 8), 256, 0, stream>>>(amb, U, s1, s2, x12);

        mfma_gemm<B_NN, EPI_SILU><<<dim3(8, 32), 256, 0, stream>>>(
            x0, 256, Wffa_l, 512, nullptr, fft, 512, N_, 256, 512, 1.f, 256, 1, 0, 0, 0);
        mfma_gemm<B_NN, EPI_ACCUM><<<dim3(4, 32), 256, 0, stream>>>(
            fft, 512, Wffb_l, 256, nullptr, x0, 256, N_, 512, 256, 1.f, 512, 1, 0, 0, 0);

        invar_kernel<<<N_, 256, 0, stream>>>(x0, x12, inv);
        mfma_gemm<B_NN, EPI_SIGMOID><<<dim3(3, 32), 256, 0, stream>>>(
            inv, F_, Wg_l, 160, nullptr, gm, 160, N_, F_, 160, 1.f, F_, 1, 0, 0, 0);
        gate_kernel<<<(N_ * X12W + 255) / 256, 256, 0, stream>>>(gm, x12);
    }

    mfma_gemm<B_NN, EPI_STORE><<<dim3(1, 32), 256, 0, stream>>>(
        x0, 256, outW, NC_, outB, out, NC_, N_, 256, NC_, 1.f, 256, 1, 0, 0, 0);
}

// Round 9
// 1484.026 us; speedup vs baseline: 6.3509x; 1.0573x over previous
//
#include <hip/hip_runtime.h>
#include <math.h>

#define N_    2048
#define D0_   256
#define D1_   128
#define D2_   32
#define F_    416
#define H_    4
#define DH_   64
#define L_    4
#define NC_   10
#define C2_   1.7320508075688772f
#define X12W  544   // x1 (128*3) | x2 (32*5) combined row width

typedef unsigned short u16;
typedef __attribute__((ext_vector_type(8))) short short8v;
typedef __attribute__((ext_vector_type(4))) float f32x4;

union U8 { u16 u[8]; short8v v; };

__device__ __forceinline__ u16 f2bf(float f) {
    union { float f; unsigned int u; } x; x.f = f;
    unsigned int r = x.u + 0x7FFFu + ((x.u >> 16) & 1u);
    return (u16)(r >> 16);
}
__device__ __forceinline__ float bf2f(u16 u) {
    union { float f; unsigned int u; } x; x.u = ((unsigned int)u) << 16;
    return x.f;
}

__device__ __forceinline__ f32x4 mfma16(short8v a, short8v b, f32x4 c) {
    return __builtin_amdgcn_mfma_f32_16x16x32_bf16(a, b, c, 0, 0, 0);
}

// ================= MFMA GEMM: f32 in (cast to bf16), epilogues ===========
// blockIdx.z = h*zk + kz : h = head (A+=h*Ah, B+=h*Bh, C+=h*Ch), kz = K-split.
enum { B_NN = 0, B_NT = 1 };
enum { EPI_STORE = 0, EPI_SILU = 1, EPI_SIGMOID = 2, EPI_ACCUM = 3, EPI_ATOMIC = 4,
       EPI_STOREB = 5 };  // store bf16 (C cast to u16*)

template<int BLAY, int EPI>
__global__ __launch_bounds__(256) void mfma_gemm(
    const float* __restrict__ A, int lda,
    const float* __restrict__ B, int ldb,
    const float* __restrict__ bias,
    float* __restrict__ C, int ldc,
    int M, int K, int Nn, float scale, int kchunk,
    int zk, long long Ah, long long Bh, long long Ch)
{
    __shared__ __align__(16) u16 As[64][40];
    __shared__ __align__(16) u16 Bs[64][40];
    const int t = threadIdx.x;
    const int bm = blockIdx.y * 64, bn = blockIdx.x * 64;
    const int hz = blockIdx.z / zk, kz = blockIdx.z % zk;
    A += (size_t)hz * Ah; B += (size_t)hz * Bh;
    const int lane = t & 63, w = t >> 6;
    const int r0 = (w >> 1) * 32, c0 = (w & 1) * 32;
    const int fr = lane & 15, fk = (lane >> 4) * 8;
    const int ml = t >> 2, k8 = (t & 3) * 8;
    const int kbeg = kz * kchunk;
    const int kend = (kbeg + kchunk < K) ? kbeg + kchunk : K;
    f32x4 acc[2][2] = {};

    for (int k0 = kbeg; k0 < kend; k0 += 32) {
        {
            U8 u;
            if (((lda & 3) == 0) && (k0 + 32 <= kend)) {
                const float* ap = A + (size_t)(bm + ml) * lda + k0 + k8;
                float4 a0 = *(const float4*)ap;
                float4 a1 = *(const float4*)(ap + 4);
                u.u[0]=f2bf(a0.x); u.u[1]=f2bf(a0.y); u.u[2]=f2bf(a0.z); u.u[3]=f2bf(a0.w);
                u.u[4]=f2bf(a1.x); u.u[5]=f2bf(a1.y); u.u[6]=f2bf(a1.z); u.u[7]=f2bf(a1.w);
            } else {
#pragma unroll
                for (int j = 0; j < 8; ++j) {
                    int kk = k0 + k8 + j;
                    u.u[j] = f2bf(kk < kend ? A[(size_t)(bm + ml) * lda + kk] : 0.f);
                }
            }
            *(short8v*)&As[ml][k8] = u.v;
        }
        {
            U8 u;
            if (BLAY == B_NT) {
                if (((ldb & 3) == 0) && (k0 + 32 <= kend) && (bn + ml < Nn)) {
                    const float* bp = B + (size_t)(bn + ml) * ldb + k0 + k8;
                    float4 b0 = *(const float4*)bp;
                    float4 b1 = *(const float4*)(bp + 4);
                    u.u[0]=f2bf(b0.x); u.u[1]=f2bf(b0.y); u.u[2]=f2bf(b0.z); u.u[3]=f2bf(b0.w);
                    u.u[4]=f2bf(b1.x); u.u[5]=f2bf(b1.y); u.u[6]=f2bf(b1.z); u.u[7]=f2bf(b1.w);
                } else {
#pragma unroll
                    for (int j = 0; j < 8; ++j) {
                        int kk = k0 + k8 + j;
                        u.u[j] = f2bf((kk < kend && bn + ml < Nn)
                                      ? B[(size_t)(bn + ml) * ldb + kk] : 0.f);
                    }
                }
            } else {
                int nc = bn + ml;
#pragma unroll
                for (int j = 0; j < 8; ++j) {
                    int kk = k0 + k8 + j;
                    u.u[j] = f2bf((kk < kend && nc < Nn) ? B[(size_t)kk * ldb + nc] : 0.f);
                }
            }
            *(short8v*)&Bs[ml][k8] = u.v;
        }
        __syncthreads();
        short8v a0 = *(const short8v*)&As[r0 + fr][fk];
        short8v a1 = *(const short8v*)&As[r0 + 16 + fr][fk];
        short8v b0 = *(const short8v*)&Bs[c0 + fr][fk];
        short8v b1 = *(const short8v*)&Bs[c0 + 16 + fr][fk];
        acc[0][0] = mfma16(a0, b0, acc[0][0]);
        acc[0][1] = mfma16(a0, b1, acc[0][1]);
        acc[1][0] = mfma16(a1, b0, acc[1][0]);
        acc[1][1] = mfma16(a1, b1, acc[1][1]);
        __syncthreads();
    }
#pragma unroll
    for (int mi = 0; mi < 2; ++mi)
#pragma unroll
    for (int ni = 0; ni < 2; ++ni)
#pragma unroll
    for (int r = 0; r < 4; ++r) {
        int row = bm + r0 + mi * 16 + ((lane >> 4) << 2) + r;
        int col = bn + c0 + ni * 16 + fr;
        if (col >= Nn) continue;
        float v = acc[mi][ni][r];
        if (EPI == EPI_STOREB) {
            ((u16*)C + (size_t)hz * Ch)[(size_t)row * ldc + col] = f2bf(v * scale);
        } else {
            float* cp = C + (size_t)hz * Ch + (size_t)row * ldc + col;
            if (EPI == EPI_STORE)   *cp = v * scale + (bias ? bias[col] : 0.f);
            if (EPI == EPI_SILU)    *cp = v / (1.f + expf(-v));
            if (EPI == EPI_SIGMOID) *cp = 1.f / (1.f + expf(-v));
            if (EPI == EPI_ACCUM)   *cp += v;
            if (EPI == EPI_ATOMIC)  atomicAdd(cp, v);
        }
    }
}

// --------- transpose: in [R][C] f32 -> out [C][R] bf16 (R multiple of 64) ---------
__global__ __launch_bounds__(256) void transpose_bf16(
    const float* __restrict__ in, u16* __restrict__ outT, int R, int C)
{
    __shared__ float tile[64][65];
    const int br = blockIdx.y * 64, bc = blockIdx.x * 64;
    const int t = threadIdx.x, lc = t & 63, q = t >> 6;
#pragma unroll 4
    for (int r = 0; r < 16; ++r) {
        int row = br + q * 16 + r, col = bc + lc;
        tile[q * 16 + r][lc] = (col < C) ? in[(size_t)row * C + col] : 0.f;
    }
    __syncthreads();
#pragma unroll 4
    for (int r = 0; r < 16; ++r) {
        int orow = bc + q * 16 + r;   // output row = original col
        int ocol = br + lc;           // output col = original row
        if (orow < C) outT[(size_t)orow * R + ocol] = f2bf(tile[lc][q * 16 + r]);
    }
}

// ============ aggP: bf16 A [M][K], bf16 BT [Nn][K]; atomic C; z = h*zk+kz ============
template<int NB>
__global__ __launch_bounds__(256) void aggP(
    const u16* __restrict__ A, int lda,
    const u16* __restrict__ BT, int ldk,
    float* __restrict__ C, int ldc,
    int K, int Nn, int kchunk,
    int zk, long long Ah, long long Bh, long long Ch)
{
    __shared__ __align__(16) u16 As[64][40];
    __shared__ __align__(16) u16 Bs[NB][64][40];
    const int t = threadIdx.x;
    const int bm = blockIdx.y * 64, bn0 = blockIdx.x * 64 * NB;
    const int hz = blockIdx.z / zk, kz = blockIdx.z % zk;
    A += (size_t)hz * Ah; BT += (size_t)hz * Bh; C += (size_t)hz * Ch;
    const int lane = t & 63, w = t >> 6;
    const int r0 = (w >> 1) * 32, c0 = (w & 1) * 32;
    const int fr = lane & 15, fk = (lane >> 4) * 8;
    const int ml = t >> 2, k8 = (t & 3) * 8;
    const int kbeg = kz * kchunk;
    const int kend = (kbeg + kchunk < K) ? kbeg + kchunk : K;
    f32x4 acc[NB][2][2] = {};

    for (int k0 = kbeg; k0 < kend; k0 += 32) {
        *(short8v*)&As[ml][k8] = *(const short8v*)(A + (size_t)(bm + ml) * lda + k0 + k8);
#pragma unroll
        for (int nb = 0; nb < NB; ++nb) {
            int nc = bn0 + nb * 64 + ml;
            short8v z = {};
            *(short8v*)&Bs[nb][ml][k8] = (nc < Nn)
                ? *(const short8v*)(BT + (size_t)nc * ldk + k0 + k8) : z;
        }
        __syncthreads();
        short8v a0 = *(const short8v*)&As[r0 + fr][fk];
        short8v a1 = *(const short8v*)&As[r0 + 16 + fr][fk];
#pragma unroll
        for (int nb = 0; nb < NB; ++nb) {
            short8v b0 = *(const short8v*)&Bs[nb][c0 + fr][fk];
            short8v b1 = *(const short8v*)&Bs[nb][c0 + 16 + fr][fk];
            acc[nb][0][0] = mfma16(a0, b0, acc[nb][0][0]);
            acc[nb][0][1] = mfma16(a0, b1, acc[nb][0][1]);
            acc[nb][1][0] = mfma16(a1, b0, acc[nb][1][0]);
            acc[nb][1][1] = mfma16(a1, b1, acc[nb][1][1]);
        }
        __syncthreads();
    }
#pragma unroll
    for (int nb = 0; nb < NB; ++nb)
#pragma unroll
    for (int mi = 0; mi < 2; ++mi)
#pragma unroll
    for (int ni = 0; ni < 2; ++ni)
#pragma unroll
    for (int r = 0; r < 4; ++r) {
        int row = bm + r0 + mi * 16 + ((lane >> 4) << 2) + r;
        int col = bn0 + nb * 64 + c0 + ni * 16 + fr;
        if (col >= Nn) continue;
        atomicAdd(C + (size_t)row * ldc + col, acc[nb][mi][ni][r]);
    }
}

// ---------------- u precompute: U[c][n][m] bf16 (24 MB) --------
__global__ void ucompute_kernel(const float* __restrict__ pos, u16* __restrict__ U) {
    int idx = blockIdx.x * 256 + threadIdx.x;
    int n = idx >> 11, m = idx & (N_ - 1);
    float rx = pos[m * 3 + 0] - pos[n * 3 + 0];
    float ry = pos[m * 3 + 1] - pos[n * 3 + 1];
    float rz = pos[m * 3 + 2] - pos[n * 3 + 2];
    float d2 = rx * rx + ry * ry + rz * rz;
    bool valid = d2 > 1e-12f;
    float rinv = valid ? rsqrtf(d2) : 0.f;
    size_t base = (size_t)n * N_ + m;
    const size_t CS = (size_t)N_ * N_;
    U[base]          = f2bf(rx * rinv);
    U[base + CS]     = f2bf(ry * rinv);
    U[base + 2 * CS] = f2bf(rz * rinv);
}

// ============ mixc: one Y-channel per block -> dense Macc atomics ============
// grid (16, 32, 8): z = channel (0-2 deg1, 3-7 deg2), kchunk 256 both degs.
//   deg1: gx = coltile(2) * ks(8);  deg2: gx = ks(8), gx>=8 exits.
// Macc layout: deg1 ch c: [c][n][128]; deg2 ch c: base 3*N*128 + [c][n][32].
__global__ __launch_bounds__(256) void mixc_kernel(
    const u16* __restrict__ amb, const u16* __restrict__ U,
    const u16* __restrict__ s1T, const u16* __restrict__ s2T,
    float* __restrict__ Macc)
{
    const int ch = blockIdx.z;
    const int gx = blockIdx.x;
    const bool deg1 = ch < 3;
    if (!deg1 && gx >= 8) return;
    const int bm = blockIdx.y * 64;
    const size_t CS = (size_t)N_ * N_;
    const int colbase = deg1 ? (gx & 1) * 64 : 0;
    const int ks      = deg1 ? (gx >> 1) : gx;
    const u16* BT     = deg1 ? s1T : s2T;
    __shared__ __align__(16) u16 As[64][40];
    __shared__ __align__(16) u16 Bs[64][40];
    const int t = threadIdx.x, lane = t & 63, w = t >> 6;
    const int r0 = (w >> 1) * 32, c0 = (w & 1) * 32;
    const int fr = lane & 15, fk = (lane >> 4) * 8;
    const int ml = t >> 2, k8 = (t & 3) * 8;
    const int kbeg = ks * 256, kend = kbeg + 256;
    f32x4 acc[2][2] = {};

    for (int m0 = kbeg; m0 < kend; m0 += 32) {
        const size_t off = (size_t)(bm + ml) * N_ + m0 + k8;
        U8 am8; am8.v = *(const short8v*)(amb + off);
        U8 o;
        if (deg1) {
            U8 uv; uv.v = *(const short8v*)(U + (size_t)ch * CS + off);
#pragma unroll
            for (int j = 0; j < 8; ++j)
                o.u[j] = f2bf(bf2f(am8.u[j]) * bf2f(uv.u[j]));
        } else {
            U8 xv, yv, zv;
            xv.v = *(const short8v*)(U + off);
            yv.v = *(const short8v*)(U + CS + off);
            zv.v = *(const short8v*)(U + 2 * CS + off);
#pragma unroll
            for (int j = 0; j < 8; ++j) {
                float a = bf2f(am8.u[j]);
                float ux = bf2f(xv.u[j]), uy = bf2f(yv.u[j]), uz = bf2f(zv.u[j]);
                float y;
                if      (ch == 3) y = C2_ * ux * uy;
                else if (ch == 4) y = C2_ * uy * uz;
                else if (ch == 5) y = (ux*ux + uy*uy + uz*uz > 0.5f)
                                      ? 0.5f * (3.f * uz * uz - 1.f) : 0.f;
                else if (ch == 6) y = C2_ * ux * uz;
                else              y = 0.5f * C2_ * (ux * ux - uy * uy);
                o.u[j] = f2bf(a * y);
            }
        }
        *(short8v*)&As[ml][k8] = o.v;
        {
            int nc = colbase + ml;
            short8v z = {};
            *(short8v*)&Bs[ml][k8] = (deg1 || nc < 32)
                ? *(const short8v*)(BT + (size_t)nc * N_ + m0 + k8) : z;
        }
        __syncthreads();
        short8v a0 = *(const short8v*)&As[r0 + fr][fk];
        short8v a1 = *(const short8v*)&As[r0 + 16 + fr][fk];
        short8v b0 = *(const short8v*)&Bs[c0 + fr][fk];
        short8v b1 = *(const short8v*)&Bs[c0 + 16 + fr][fk];
        acc[0][0] = mfma16(a0, b0, acc[0][0]);
        acc[0][1] = mfma16(a0, b1, acc[0][1]);
        acc[1][0] = mfma16(a1, b0, acc[1][0]);
        acc[1][1] = mfma16(a1, b1, acc[1][1]);
        __syncthreads();
    }
#pragma unroll
    for (int mi = 0; mi < 2; ++mi)
#pragma unroll
    for (int ni = 0; ni < 2; ++ni)
#pragma unroll
    for (int r = 0; r < 4; ++r) {
        int row = bm + r0 + mi * 16 + ((lane >> 4) << 2) + r;
        int col = colbase + c0 + ni * 16 + fr;
        float v = acc[mi][ni][r];
        if (deg1)
            atomicAdd(&Macc[(size_t)ch * N_ * 128 + (size_t)row * 128 + col], v);
        else if (col < 32)
            atomicAdd(&Macc[(size_t)3 * N_ * 128 + (size_t)(ch - 3) * N_ * 32
                            + (size_t)row * 32 + col], v);
    }
}

// -------- combine: x12 += Macc (scatter from channel-major to interleaved) --------
__global__ void mix_combine(const float* __restrict__ Macc, float* __restrict__ x12) {
    int idx = blockIdx.x * 256 + threadIdx.x;
    if (idx >= N_ * X12W) return;
    int n = idx / X12W, j = idx % X12W;
    float v;
    if (j < 384) {
        int e = j / 3, c = j - 3 * e;
        v = Macc[(size_t)c * N_ * 128 + (size_t)n * 128 + e];
    } else {
        int jj = j - 384;
        int e = jj / 5, c = jj - 5 * e;
        v = Macc[(size_t)3 * N_ * 128 + (size_t)c * N_ * 32 + (size_t)n * 32 + e];
    }
    x12[idx] += v;
}

// ---------------- invariants ----------------
__global__ void invar_kernel(const float* __restrict__ x0, const float* __restrict__ x12,
                             float* __restrict__ inv) {
    int n = blockIdx.x, t = threadIdx.x;
    inv[(size_t)n * F_ + t] = x0[(size_t)n * D0_ + t];
    if (t < 128) {
        const float* p = x12 + (size_t)n * X12W + t * 3;
        inv[(size_t)n * F_ + 256 + t] = sqrtf(p[0]*p[0] + p[1]*p[1] + p[2]*p[2]);
    }
    if (t < 32) {
        const float* p = x12 + (size_t)n * X12W + 384 + t * 5;
        inv[(size_t)n * F_ + 384 + t] =
            sqrtf(p[0]*p[0] + p[1]*p[1] + p[2]*p[2] + p[3]*p[3] + p[4]*p[4]);
    }
}

// ---------------- Vflat[m, e*3+c] = sum_d x1[m,d,c] Wv1[d,e] ----------------
__global__ void v1_kernel(const float* __restrict__ x12, const float* __restrict__ W,
                          float* __restrict__ Vflat) {
    int m = blockIdx.x, t = threadIdx.x;  // 384
    __shared__ float sh[384];
    sh[t] = x12[(size_t)m * X12W + t];
    __syncthreads();
    int e = t / 3, c = t % 3;
    float acc = 0.f;
#pragma unroll 4
    for (int d = 0; d < 128; ++d)
        acc = fmaf(sh[d * 3 + c], W[d * 128 + e], acc);
    Vflat[(size_t)m * X12W + t] = acc;
}

__global__ void v2_kernel(const float* __restrict__ x12, const float* __restrict__ W,
                          float* __restrict__ Vflat) {
    int m = blockIdx.x, t = threadIdx.x;  // 192, 160 active
    __shared__ float sh[160];
    if (t < 160) sh[t] = x12[(size_t)m * X12W + 384 + t];
    __syncthreads();
    if (t < 160) {
        int e = t / 5, c = t % 5;
        float acc = 0.f;
#pragma unroll 4
        for (int d = 0; d < 32; ++d)
            acc = fmaf(sh[d * 5 + c], W[d * 32 + e], acc);
        Vflat[(size_t)m * X12W + 384 + t] = acc;
    }
}

// ------- fused 4-head softmax: normalize P_h (bf16, in place) + write am bf16 -------
__global__ void softmax4(u16* __restrict__ Sb, u16* __restrict__ amb) {
    int n = blockIdx.x, t = threadIdx.x;  // 256 threads, 8 elems each
    __shared__ float red[256];
    const size_t NN = (size_t)N_ * N_;
    float amv[8] = {};
    for (int h = 0; h < H_; ++h) {
        u16* Sp = Sb + (size_t)h * NN + (size_t)n * N_ + t * 8;
        U8 sv; sv.v = *(const short8v*)Sp;
        float s[8];
#pragma unroll
        for (int j = 0; j < 8; ++j) s[j] = bf2f(sv.u[j]);
        float mx = s[0];
#pragma unroll
        for (int j = 1; j < 8; ++j) mx = fmaxf(mx, s[j]);
        red[t] = mx; __syncthreads();
        for (int st = 128; st > 0; st >>= 1) { if (t < st) red[t] = fmaxf(red[t], red[t + st]); __syncthreads(); }
        mx = red[0]; __syncthreads();
        float sum = 0.f;
#pragma unroll
        for (int j = 0; j < 8; ++j) { s[j] = expf(s[j] - mx); sum += s[j]; }
        red[t] = sum; __syncthreads();
        for (int st = 128; st > 0; st >>= 1) { if (t < st) red[t] += red[t + st]; __syncthreads(); }
        float rinv = 1.f / red[0]; __syncthreads();
        U8 pv;
#pragma unroll
        for (int j = 0; j < 8; ++j) {
            float p = s[j] * rinv;
            pv.u[j] = f2bf(p);
            amv[j] += 0.25f * p;
        }
        *(short8v*)Sp = pv.v;
    }
    U8 av;
#pragma unroll
    for (int j = 0; j < 8; ++j) av.u[j] = f2bf(amv[j]);
    *(short8v*)(amb + (size_t)n * N_ + t * 8) = av.v;
}

// ---------------- gating over x12 ----------------
__global__ void gate_kernel(const float* __restrict__ g, float* __restrict__ x12) {
    int idx = blockIdx.x * 256 + threadIdx.x;
    if (idx >= N_ * X12W) return;
    int n = idx / X12W, j = idx % X12W;
    float gv = (j < 384) ? g[n * 160 + j / 3] : g[n * 160 + 128 + (j - 384) / 5];
    x12[idx] *= gv;
}

extern "C" void kernel_launch(void* const* d_in, const int* in_sizes, int n_in,
                              void* d_out, int out_size, void* d_ws, size_t ws_size,
                              hipStream_t stream) {
    const float* x    = (const float*)d_in[0];
    const float* pos  = (const float*)d_in[1];
    const float* embW = (const float*)d_in[2];
    const float* embB = (const float*)d_in[3];
    const float* Wq   = (const float*)d_in[4];
    const float* Wk   = (const float*)d_in[5];
    const float* Wv0  = (const float*)d_in[6];
    const float* Wv1  = (const float*)d_in[7];
    const float* Wv2  = (const float*)d_in[8];
    const float* Ws1  = (const float*)d_in[9];
    const float* Ws2  = (const float*)d_in[10];
    const float* Wffa = (const float*)d_in[11];
    const float* Wffb = (const float*)d_in[12];
    const float* Wg   = (const float*)d_in[13];
    const float* outW = (const float*)d_in[14];
    const float* outB = (const float*)d_in[15];
    float* out = (float*)d_out;

    const size_t NN = (size_t)N_ * N_;
    float* p = (float*)d_ws;
    float* x0    = p; p += N_ * D0_;
    float* x12   = p; p += N_ * X12W;
    float* inv   = p; p += N_ * F_;
    float* q     = p; p += N_ * D0_;
    float* k     = p; p += N_ * D0_;
    float* v0    = p; p += N_ * D0_;
    float* Vflat = p; p += N_ * X12W;
    float* s1    = p; p += N_ * D1_;
    float* s2    = p; p += N_ * D2_;
    float* fft   = p; p += N_ * 512;
    float* gm    = p; p += N_ * 160;
    float* Macc  = p; p += 3 * N_ * 128 + 5 * N_ * 32;   // 4.5 MB dense mix accum
    u16* ub   = (u16*)p;
    u16* Sb   = ub; ub += 4 * NN;        // 4 heads' S/P, bf16 (32 MB)
    u16* amb  = ub; ub += NN;            // head-mean attention, bf16 (8 MB)
    u16* U    = ub; ub += 3 * NN;        // unit vectors (24 MB)
    u16* v0T  = ub; ub += D0_ * N_;      // [256][2048]
    u16* s1T  = ub; ub += D1_ * N_;      // [128][2048]
    u16* s2T  = ub; ub += D2_ * N_;      // [32][2048]
    u16* VflatT = ub; ub += X12W * N_;   // [544][2048]

    hipMemsetAsync(x12, 0, (size_t)N_ * X12W * sizeof(float), stream);
    ucompute_kernel<<<(N_ * N_) / 256, 256, 0, stream>>>(pos, U);

    mfma_gemm<B_NN, EPI_STORE><<<dim3(4, 32), 256, 0, stream>>>(
        x, 118, embW, 256, embB, x0, 256, N_, 118, 256, 1.f, 118, 1, 0, 0, 0);

    for (int l = 0; l < L_; ++l) {
        const float* Wq_l   = Wq   + (size_t)l * F_ * 256;
        const float* Wk_l   = Wk   + (size_t)l * F_ * 256;
        const float* Wv0_l  = Wv0  + (size_t)l * 256 * 256;
        const float* Wv1_l  = Wv1  + (size_t)l * 128 * 128;
        const float* Wv2_l  = Wv2  + (size_t)l * 32 * 32;
        const float* Ws1_l  = Ws1  + (size_t)l * 256 * 128;
        const float* Ws2_l  = Ws2  + (size_t)l * 256 * 32;
        const float* Wffa_l = Wffa + (size_t)l * 256 * 512;
        const float* Wffb_l = Wffb + (size_t)l * 512 * 256;
        const float* Wg_l   = Wg   + (size_t)l * F_ * 160;

        hipMemsetAsync(Macc, 0, (3 * N_ * 128 + 5 * N_ * 32) * sizeof(float), stream);
        invar_kernel<<<N_, 256, 0, stream>>>(x0, x12, inv);
        mfma_gemm<B_NN, EPI_STORE><<<dim3(4, 32), 256, 0, stream>>>(
            inv, F_, Wq_l, 256, nullptr, q, 256, N_, F_, 256, 1.f, F_, 1, 0, 0, 0);
        mfma_gemm<B_NN, EPI_STORE><<<dim3(4, 32), 256, 0, stream>>>(
            inv, F_, Wk_l, 256, nullptr, k, 256, N_, F_, 256, 1.f, F_, 1, 0, 0, 0);
        mfma_gemm<B_NN, EPI_STORE><<<dim3(4, 32), 256, 0, stream>>>(
            x0, 256, Wv0_l, 256, nullptr, v0, 256, N_, 256, 256, 1.f, 256, 1, 0, 0, 0);
        mfma_gemm<B_NN, EPI_STORE><<<dim3(2, 32), 256, 0, stream>>>(
            x0, 256, Ws1_l, 128, nullptr, s1, 128, N_, 256, 128, 1.f, 256, 1, 0, 0, 0);
        mfma_gemm<B_NN, EPI_STORE><<<dim3(1, 32), 256, 0, stream>>>(
            x0, 256, Ws2_l, 32, nullptr, s2, 32, N_, 256, 32, 1.f, 256, 1, 0, 0, 0);
        v1_kernel<<<N_, 384, 0, stream>>>(x12, Wv1_l, Vflat);
        v2_kernel<<<N_, 192, 0, stream>>>(x12, Wv2_l, Vflat);

        // bf16 transposed activation operands
        transpose_bf16<<<dim3(4, 32), 256, 0, stream>>>(v0, v0T, N_, 256);
        transpose_bf16<<<dim3(2, 32), 256, 0, stream>>>(s1, s1T, N_, 128);
        transpose_bf16<<<dim3(1, 32), 256, 0, stream>>>(s2, s2T, N_, 32);
        transpose_bf16<<<dim3(9, 32), 256, 0, stream>>>(Vflat, VflatT, N_, X12W);

        // S_h = (q_h @ k_h^T)/8 -> bf16, all 4 heads in one launch (z = head)
        mfma_gemm<B_NT, EPI_STOREB><<<dim3(32, 32, 4), 256, 0, stream>>>(
            q, 256, k, 256, nullptr, (float*)Sb, N_, N_, 64, N_, 0.125f, 64,
            1, 64, 64, (long long)NN);
        softmax4<<<N_, 256, 0, stream>>>(Sb, amb);
        // x0[:, h*64:+64] += P_h @ v0_h : all heads, split-K=8 (z = h*8+ks)
        aggP<1><<<dim3(1, 32, 32), 256, 0, stream>>>(
            Sb, N_, v0T, N_, x0, 256, N_, 64, 256,
            8, (long long)NN, (long long)(64 * N_), 64);

        // agg1+agg2: x12 += am @ Vflat  (3 col-tiles/block, split-K=4)
        aggP<3><<<dim3(3, 32, 4), 256, 0, stream>>>(
            amb, N_, VflatT, N_, x12, X12W, N_, X12W, 512,
            4, 0, 0, 0);
        // mix: one channel per block -> dense Macc, then combine
        mixc_kernel<<<dim3(16, 32, 8), 256, 0, stream>>>(amb, U, s1T, s2T, Macc);
        mix_combine<<<(N_ * X12W + 255) / 256, 256, 0, stream>>>(Macc, x12);

        mfma_gemm<B_NN, EPI_SILU><<<dim3(8, 32), 256, 0, stream>>>(
            x0, 256, Wffa_l, 512, nullptr, fft, 512, N_, 256, 512, 1.f, 256, 1, 0, 0, 0);
        mfma_gemm<B_NN, EPI_ACCUM><<<dim3(4, 32), 256, 0, stream>>>(
            fft, 512, Wffb_l, 256, nullptr, x0, 256, N_, 512, 256, 1.f, 512, 1, 0, 0, 0);

        invar_kernel<<<N_, 256, 0, stream>>>(x0, x12, inv);
        mfma_gemm<B_NN, EPI_SIGMOID><<<dim3(3, 32), 256, 0, stream>>>(
            inv, F_, Wg_l, 160, nullptr, gm, 160, N_, F_, 160, 1.f, F_, 1, 0, 0, 0);
        gate_kernel<<<(N_ * X12W + 255) / 256, 256, 0, stream>>>(gm, x12);
    }

    mfma_gemm<B_NN, EPI_STORE><<<dim3(1, 32), 256, 0, stream>>>(
        x0, 256, outW, NC_, outB, out, NC_, N_, 256, NC_, 1.f, 256, 1, 0, 0, 0);
}